// Round 9
// baseline (1558.432 us; speedup 1.0000x reference)
//
#include <hip/hip_runtime.h>
#include <stdint.h>
#include <string.h>
#include <math.h>

#define NB 128   // batch
#define NN 512   // nodes
#define NH 256   // hidden
#define NR 3
#define TH_TAIL 10

typedef __attribute__((ext_vector_type(8))) short bh8;   // 8 x bf16
typedef __attribute__((ext_vector_type(4))) float f32x4;

// ======================= numpy RNG reproduction (host) =======================
struct Pcg {
  __uint128_t state, inc;
  bool has32; uint32_t buf32;
};

static const __uint128_t PCG_MULT =
    (((__uint128_t)2549297995355413924ULL) << 64) | 4865540595714422341ULL;

static inline uint64_t pcg_next64(Pcg& s) {
  s.state = s.state * PCG_MULT + s.inc;
  uint64_t hi = (uint64_t)(s.state >> 64), lo = (uint64_t)s.state;
  uint64_t x = hi ^ lo;
  unsigned rot = (unsigned)(s.state >> 122) & 63u;
  return (x >> rot) | (x << ((64u - rot) & 63u));
}
static inline uint32_t pcg_next32(Pcg& s) {
  if (s.has32) { s.has32 = false; return s.buf32; }
  uint64_t n = pcg_next64(s);
  s.has32 = true; s.buf32 = (uint32_t)(n >> 32);
  return (uint32_t)n;
}
static inline uint64_t pcg_bounded(Pcg& s, uint64_t high) {
  uint64_t rng = high - 1;
  if (rng == 0) return 0;
  uint32_t rng_excl = (uint32_t)rng + 1u;
  uint64_t m = (uint64_t)pcg_next32(s) * (uint64_t)rng_excl;
  uint32_t leftover = (uint32_t)m;
  if (leftover < rng_excl) {
    uint32_t threshold = (uint32_t)((0xFFFFFFFFu - (uint32_t)rng) % rng_excl);
    while (leftover < threshold) {
      m = (uint64_t)pcg_next32(s) * (uint64_t)rng_excl;
      leftover = (uint32_t)m;
    }
  }
  return m >> 32;
}
static inline double pcg_double(Pcg& s) {
  return (double)(pcg_next64(s) >> 11) * (1.0 / 9007199254740992.0);
}

static void pcg_seed0(Pcg& s) {
  uint32_t pool[4];
  uint32_t hc = 0x43b0d7e5u;
  auto hashmix = [&hc](uint32_t v) -> uint32_t {
    v ^= hc; hc *= 0x931e8875u; v *= hc; v ^= v >> 16; return v;
  };
  auto mix = [](uint32_t x, uint32_t y) -> uint32_t {
    uint32_t r = 0xca01f9ddu * x - 0x4973f715u * y; r ^= r >> 16; return r;
  };
  for (int i = 0; i < 4; i++) pool[i] = hashmix(0u);
  for (int src = 0; src < 4; src++)
    for (int dst = 0; dst < 4; dst++)
      if (src != dst) pool[dst] = mix(pool[dst], hashmix(pool[src]));
  uint32_t gs[8]; uint32_t hb = 0x8b51f9ddu;
  for (int i = 0; i < 8; i++) {
    uint32_t dv = pool[i & 3];
    dv ^= hb; hb *= 0x58f38dedu; dv *= hb; dv ^= dv >> 16;
    gs[i] = dv;
  }
  uint64_t w0 = (uint64_t)gs[0] | ((uint64_t)gs[1] << 32);
  uint64_t w1 = (uint64_t)gs[2] | ((uint64_t)gs[3] << 32);
  uint64_t w2 = (uint64_t)gs[4] | ((uint64_t)gs[5] << 32);
  uint64_t w3 = (uint64_t)gs[6] | ((uint64_t)gs[7] << 32);
  __uint128_t initstate = (((__uint128_t)w0) << 64) | w1;
  __uint128_t initseq   = (((__uint128_t)w2) << 64) | w3;
  s.state = 0;
  s.inc = (initseq << 1) | 1;
  s.state = s.state * PCG_MULT + s.inc;
  s.state += initstate;
  s.state = s.state * PCG_MULT + s.inc;
  s.has32 = false; s.buf32 = 0;
}

// ======================= tree build (host) =======================
struct TreeMeta {
  int nodes[512];    // internal nodes, level-ordered (deepest first)
  int cstart[512];
  int ccount[512];
  int echild[512];   // all-children edges, node-grouped
  int erel[512];
  float edecay[512];
  int cechild[512];  // csum edges (internal children only), node-grouped
  int cerel[512];
  float cedec[512];
  int cens[513];     // per meta-node index -> first csum edge (+ sentinel)
};
struct HostTree {
  TreeMeta meta;
  int n_levels;
  int level_off[520];
  int level_M[520];
};

static void build_tree_host(HostTree& T) {
  Pcg st; pcg_seed0(st);
  int parent[NN], depth[NN], rel[NN];
  unsigned char virt[NN];
  parent[0] = 0; depth[0] = 0;
  for (int i = 1; i < NN; i++) parent[i] = (int)pcg_bounded(st, (uint64_t)i);
  for (int i = 1; i < NN; i++) depth[i] = depth[parent[i]] + 1;
  for (int i = 0; i < NN; i++) rel[i] = (int)pcg_bounded(st, (uint64_t)NR);
  for (int i = 0; i < NN; i++) virt[i] = (pcg_double(st) < 0.1) ? 1 : 0;

  int childcnt[NN]; memset(childcnt, 0, sizeof(childcnt));
  for (int i = 1; i < NN; i++) childcnt[parent[i]]++;
  int maxd = 0;
  for (int i = 0; i < NN; i++) if (depth[i] > maxd) maxd = depth[i];

  int ni = 0, ne = 0, nec = 0;
  T.n_levels = 0;
  for (int d = maxd; d >= 0; d--) {
    int mstart = ni;
    for (int n = 0; n < NN; n++) {
      if (depth[n] == d && childcnt[n] > 0) {
        T.meta.nodes[ni] = n;
        T.meta.cstart[ni] = ne;
        T.meta.ccount[ni] = childcnt[n];
        T.meta.cens[ni] = nec;
        for (int i2 = 1; i2 < NN; i2++) {
          if (parent[i2] == n) {
            T.meta.echild[ne] = i2;
            T.meta.erel[ne] = rel[i2];
            T.meta.edecay[ne] = virt[i2] ? 0.7f : 1.0f;
            ne++;
            if (childcnt[i2] > 0) {  // leaf children contribute exactly 0 to c_sum
              T.meta.cechild[nec] = i2;
              T.meta.cerel[nec] = rel[i2];
              T.meta.cedec[nec] = virt[i2] ? 0.7f : 1.0f;
              nec++;
            }
          }
        }
        ni++;
      }
    }
    if (ni > mstart) {
      T.level_off[T.n_levels] = mstart;
      T.level_M[T.n_levels] = ni - mstart;
      T.n_levels++;
    }
  }
  T.meta.cens[ni] = nec;
}

// ======================= device helpers =======================
__device__ __forceinline__ uint16_t f2bf(float f) {
  uint32_t u = __float_as_uint(f);
  return (uint16_t)((u + 0x7fffu + ((u >> 16) & 1u)) >> 16);
}
__device__ __forceinline__ float bf2f(uint16_t b) {
  return __uint_as_float(((uint32_t)b) << 16);
}
__device__ __forceinline__ float sigm(float x) {
  return 1.f / (1.f + expf(-x));
}

// Stage rows x 64 bf16 tile into LDS with XOR swizzle: elem ^= (row&7)<<3
__device__ __forceinline__ void stage_bf16(uint16_t* __restrict__ sm,
    const uint16_t* __restrict__ src, int stride, int rows) {
  const int chunks = rows << 3;
  for (int cch = threadIdx.x; cch < chunks; cch += 256) {
    const int row = cch >> 3, k = (cch & 7) << 3;
    uint4 v = *(const uint4*)(src + (size_t)row * stride + k);
    *(uint4*)(sm + (((row << 6) + k) ^ ((row & 7) << 3))) = v;
  }
}
__device__ __forceinline__ void stage_f32(uint16_t* __restrict__ sm,
    const float* __restrict__ src, int stride, int rows) {
  const int chunks = rows << 3;
  for (int cch = threadIdx.x; cch < chunks; cch += 256) {
    const int row = cch >> 3, k = (cch & 7) << 3;
    const float* p = src + (size_t)row * stride + k;
    float4 a = *(const float4*)p, b = *(const float4*)(p + 4);
    uint4 w;
    w.x = (uint32_t)f2bf(a.x) | ((uint32_t)f2bf(a.y) << 16);
    w.y = (uint32_t)f2bf(a.z) | ((uint32_t)f2bf(a.w) << 16);
    w.z = (uint32_t)f2bf(b.x) | ((uint32_t)f2bf(b.y) << 16);
    w.w = (uint32_t)f2bf(b.z) | ((uint32_t)f2bf(b.w) << 16);
    *(uint4*)(sm + (((row << 6) + k) ^ ((row & 7) << 3))) = w;
  }
}
__device__ __forceinline__ bh8 fld(const uint16_t* __restrict__ sm, int row, int k) {
  return *(const bh8*)(sm + (((row << 6) + k) ^ ((row & 7) << 3)));
}

// ======================= weight prep: transpose + bf16 =======================
__global__ __launch_bounds__(256) void k_prep(const float* __restrict__ We,
    const float* __restrict__ Wf, const float* __restrict__ Wi,
    const float* __restrict__ Wo, const float* __restrict__ Wu,
    uint16_t* __restrict__ WeT, uint16_t* __restrict__ WfT,
    uint16_t* __restrict__ WgT) {
  const int i = blockIdx.x * 256 + threadIdx.x;
  if (i < 65536) {
    const int n = i >> 8, k = i & 255;
    WeT[i] = f2bf(We[k * 256 + n]);
  }
  const int i2 = i - 65536;
  if (i2 >= 0 && i2 < 196608) {
    const int r = i2 >> 16, rem = i2 & 65535, n = rem >> 8, k = rem & 255;
    WfT[i2] = f2bf(Wf[r * 65536 + k * 256 + n]);
  }
  const int i3 = i - 262144;
  if (i3 >= 0 && i3 < 393216) {
    const int g = i3 >> 17, rem = i3 & 131071, n = rem >> 9, k = rem & 511;
    const float* S = (g == 0) ? Wi : (g == 1) ? Wo : Wu;
    WgT[i3] = f2bf(S[k * 256 + n]);
  }
}

// ======================= encoder: h_bf = bf16(nf @ W_enc + b) =======================
__global__ __launch_bounds__(256) void k_enc(const float* __restrict__ nf,
    const uint16_t* __restrict__ WeT, const float* __restrict__ b_enc,
    uint16_t* __restrict__ h_bf) {
  __shared__ __align__(16) uint16_t smA[128 * 64];
  __shared__ __align__(16) uint16_t smB[128 * 64];
  const int bm = blockIdx.x * 128, bn = blockIdx.y * 128;
  const int tid = threadIdx.x, wid = tid >> 6, lane = tid & 63;
  const int wr = wid >> 1, wc2 = wid & 1, lr = lane & 15, lk = (lane >> 4) << 3;
  f32x4 acc[4][4] = {};
  for (int k0 = 0; k0 < 256; k0 += 64) {
    __syncthreads();
    stage_f32(smA, nf + (size_t)bm * NH + k0, NH, 128);
    stage_bf16(smB, WeT + (size_t)bn * 256 + k0, 256, 128);
    __syncthreads();
#pragma unroll
    for (int ks = 0; ks < 2; ks++) {
      bh8 af[4], bfr[4];
#pragma unroll
      for (int i = 0; i < 4; i++) af[i] = fld(smA, wr * 64 + i * 16 + lr, ks * 32 + lk);
#pragma unroll
      for (int j = 0; j < 4; j++) bfr[j] = fld(smB, wc2 * 64 + j * 16 + lr, ks * 32 + lk);
#pragma unroll
      for (int i = 0; i < 4; i++)
#pragma unroll
        for (int j = 0; j < 4; j++)
          acc[i][j] = __builtin_amdgcn_mfma_f32_16x16x32_bf16(af[i], bfr[j], acc[i][j], 0, 0, 0);
    }
  }
#pragma unroll
  for (int i = 0; i < 4; i++) {
#pragma unroll
    for (int j = 0; j < 4; j++) {
      const int col = bn + wc2 * 64 + j * 16 + (lane & 15);
      const float be = b_enc[col];
#pragma unroll
      for (int r = 0; r < 4; r++) {
        const int row = bm + wr * 64 + i * 16 + (lane >> 4) * 4 + r;
        h_bf[(size_t)row * NH + col] = f2bf(acc[i][j][r] + be);
      }
    }
  }
}

// ======================= fused per-level kernel, col-sliced (big levels) =======================
__global__ __launch_bounds__(256) void k_lvl(
    uint16_t* h_bf, float* c,
    const uint16_t* __restrict__ WfT, const uint16_t* __restrict__ WgT,
    const float* __restrict__ b_f, const float* __restrict__ b_i,
    const float* __restrict__ b_o, const float* __restrict__ b_u,
    const float* __restrict__ rel_emb, const float* __restrict__ w_attn,
    const float* __restrict__ b_attn, float* __restrict__ out,
    const TreeMeta* __restrict__ tm, int nb) {
  __shared__ float sc[64 * 65];                           // 16.6 KB
  __shared__ float swa[256];
  __shared__ float sRE[3];
  __shared__ int chl[64]; __shared__ int rll[64]; __shared__ float dcl[64];
  __shared__ __align__(16) uint16_t hsum[4 * 4096];       // 32 KB (64 x 256)

  const int bx = blockIdx.x, mloc = bx >> 1, b0 = (bx & 1) * 64;
  const int cslice = blockIdx.y * 64;
  const int gi = nb + mloc;
  const int nd = tm->nodes[gi], cs = tm->cstart[gi], cc = tm->ccount[gi];
  const int ce0 = tm->cens[gi], nic = tm->cens[gi + 1] - ce0;
  const int tid = threadIdx.x, wid = tid >> 6, lane = tid & 63;
  const int lr2 = lane & 15, hi4 = (lane >> 4), lk = hi4 << 3;
  const int colw = cslice + wid * 16 + lr2;  // this lane's output column

  if (tid < cc) {
    chl[tid] = tm->echild[cs + tid];
    rll[tid] = tm->erel[cs + tid];
    dcl[tid] = tm->edecay[cs + tid];
  }
  swa[tid] = w_attn[tid];
  if (wid < 3) {  // sRE[r] = rel_emb[r] . w_attn
    float p = 0.f;
#pragma unroll
    for (int i = 0; i < 4; i++) p += rel_emb[wid * NH + lane + 64 * i] * w_attn[lane + 64 * i];
#pragma unroll
    for (int off = 32; off; off >>= 1) p += __shfl_down(p, off);
    if (lane == 0) sRE[wid] = p;
  }
  __syncthreads();

  // ---- scores (full 256-dim) ----
  const int sb = tid >> 2, sq = tid & 3;  // 4 threads per batch row
  const float ba = b_attn[0];
  for (int e = 0; e < cc; e++) {
    const uint16_t* hp = h_bf + ((size_t)(b0 + sb) * NN + chl[e]) * NH + sq * 64;
    float s = 0.f;
#pragma unroll
    for (int v = 0; v < 8; v++) {
      uint4 pk = *(const uint4*)(hp + v * 8);
      const uint16_t* pe = (const uint16_t*)&pk;
#pragma unroll
      for (int q = 0; q < 8; q++) s = fmaf(bf2f(pe[q]), swa[sq * 64 + v * 8 + q], s);
    }
    s += __shfl_xor(s, 1); s += __shfl_xor(s, 2);
    if (sq == 0) sc[sb * 65 + e] = sRE[rll[e]] + dcl[e] * s + ba;
  }
  __syncthreads();
  // ---- softmax per batch row; fold decay into weight ----
  if (tid < 64) {
    float mx = -1e30f;
    for (int e = 0; e < cc; e++) mx = fmaxf(mx, sc[tid * 65 + e]);
    float ss = 0.f;
    for (int e = 0; e < cc; e++) ss += expf(sc[tid * 65 + e] - mx);
    const float inv = 1.0f / ss;
    for (int e = 0; e < cc; e++) sc[tid * 65 + e] = expf(sc[tid * 65 + e] - mx) * inv * dcl[e];
  }
  __syncthreads();

  // ---- h_sum (full 256-dim) -> LDS ----
  {
    float hs[64];
#pragma unroll
    for (int v = 0; v < 64; v++) hs[v] = 0.f;
    for (int e = 0; e < cc; e++) {
      const float w = sc[sb * 65 + e];
      const uint16_t* hp = h_bf + ((size_t)(b0 + sb) * NN + chl[e]) * NH + sq * 64;
#pragma unroll
      for (int v = 0; v < 8; v++) {
        uint4 pk = *(const uint4*)(hp + v * 8);
        const uint16_t* pe = (const uint16_t*)&pk;
#pragma unroll
        for (int q = 0; q < 8; q++) hs[v * 8 + q] = fmaf(bf2f(pe[q]), w, hs[v * 8 + q]);
      }
    }
    uint16_t* sub = hsum + sq * 4096;
#pragma unroll
    for (int v = 0; v < 32; v++) {
      uint32_t pk = (uint32_t)f2bf(hs[2 * v]) | ((uint32_t)f2bf(hs[2 * v + 1]) << 16);
      const int elem = ((sb << 6) + 2 * v) ^ ((sb & 7) << 3);
      *(uint32_t*)(sub + elem) = pk;
    }
  }

  // ---- csum for this 64-col slice: direct-global MFMA, no barriers ----
  f32x4 csum[4] = {};
  for (int e = 0; e < nic; e++) {
    const int ch = tm->cechild[ce0 + e];
    const int rel = tm->cerel[ce0 + e];
    const float dec = tm->cedec[ce0 + e];
    const uint16_t* Wr = WfT + (size_t)rel * 65536 + (size_t)colw * 256;
    f32x4 facc[4] = {};
#pragma unroll
    for (int k0 = 0; k0 < 8; k0++) {
      const int kk = k0 * 32 + lk;
      bh8 af[4];
#pragma unroll
      for (int i = 0; i < 4; i++)
        af[i] = *(const bh8*)(h_bf + ((size_t)(b0 + i * 16 + lr2) * NN + ch) * NH + kk);
      const bh8 bq = *(const bh8*)(Wr + kk);
#pragma unroll
      for (int i = 0; i < 4; i++)
        facc[i] = __builtin_amdgcn_mfma_f32_16x16x32_bf16(af[i], bq, facc[i], 0, 0, 0);
    }
    const float bfv = b_f[rel * NH + colw];
#pragma unroll
    for (int i = 0; i < 4; i++) {
#pragma unroll
      for (int r = 0; r < 4; r++) {
        const int brow = b0 + i * 16 + hi4 * 4 + r;
        const float cch = c[((size_t)brow * NN + ch) * NH + colw];
        csum[i][r] += (dec * facc[i][r] + bfv) * (dec * cch);
      }
    }
  }
  __syncthreads();  // hsum writes visible before gates reads

  // ---- gates GEMM (K=512): A = h_bf[nd] direct | hsum LDS; B = col slice ----
  f32x4 ga[3][4] = {};
#pragma unroll
  for (int k32 = 0; k32 < 16; k32++) {
    const int kk = k32 * 32 + lk;
    bh8 af[4], bq[3];
    if (k32 < 8) {
#pragma unroll
      for (int i = 0; i < 4; i++)
        af[i] = *(const bh8*)(h_bf + ((size_t)(b0 + i * 16 + lr2) * NN + nd) * NH + kk);
    } else {
      const int kx = k32 - 8;
#pragma unroll
      for (int i = 0; i < 4; i++)
        af[i] = fld(hsum + (kx >> 1) * 4096, i * 16 + lr2, (kx & 1) * 32 + lk);
    }
#pragma unroll
    for (int g = 0; g < 3; g++)
      bq[g] = *(const bh8*)(WgT + ((size_t)g << 17) + (size_t)colw * 512 + kk);
#pragma unroll
    for (int g = 0; g < 3; g++)
#pragma unroll
      for (int i = 0; i < 4; i++)
        ga[g][i] = __builtin_amdgcn_mfma_f32_16x16x32_bf16(af[i], bq[g], ga[g][i], 0, 0, 0);
  }

  const float bi_ = b_i[colw], bo_ = b_o[colw], bu_ = b_u[colw];
#pragma unroll
  for (int i = 0; i < 4; i++) {
#pragma unroll
    for (int r = 0; r < 4; r++) {
      const int brow = b0 + i * 16 + hi4 * 4 + r;
      const size_t idx = ((size_t)brow * NN + nd) * NH + colw;
      const float ig = sigm(ga[0][i][r] + bi_);
      const float og = sigm(ga[1][i][r] + bo_);
      const float ug = tanhf(ga[2][i][r] + bu_);
      const float cn = fmaf(ig, ug, csum[i][r]);
      c[idx] = cn;
      const float hn = og * tanhf(cn);
      h_bf[idx] = f2bf(hn);
      if (nd == 0) out[(size_t)brow * NH + colw] = hn;
    }
  }
}

// ======================= tail kernel: serial node walk, batch-sliced =======================
// grid = 8 blocks; block owns 16 batch rows, walks nodes [start, start+count)
// in level order (valid topological order). Fully batch-independent -> no
// cross-block deps, no atomics. Per node: scores -> softmax -> h_sum(LDS) ->
// csum (MFMA 16xN, direct global A/B) -> gates (K=512 MFMA) -> LSTM epilogue.
__global__ __launch_bounds__(256) void k_tail(
    uint16_t* h_bf, float* c,
    const uint16_t* __restrict__ WfT, const uint16_t* __restrict__ WgT,
    const float* __restrict__ b_f, const float* __restrict__ b_i,
    const float* __restrict__ b_o, const float* __restrict__ b_u,
    const float* __restrict__ rel_emb, const float* __restrict__ w_attn,
    const float* __restrict__ b_attn, float* __restrict__ out,
    const TreeMeta* __restrict__ tm, int start, int count) {
  __shared__ float sc[16 * 68];                       // [b][e] scores -> weights
  __shared__ float swaf[256];
  __shared__ float sRE[3];
  __shared__ int chl[64]; __shared__ int rll[64]; __shared__ float dcl[64];
  __shared__ __align__(16) uint16_t hsum[16 * 256];   // 8 KB, 4 subtiles [16][64] swizzled

  const int tid = threadIdx.x, wid = tid >> 6, lane = tid & 63;
  const int b0 = blockIdx.x * 16;
  const int lb = lane & 15, lq = lane >> 4;

  swaf[tid] = w_attn[tid];
  if (wid < 3) {  // sRE[r] = rel_emb[r] . w_attn
    float p = 0.f;
#pragma unroll
    for (int i = 0; i < 4; i++) p += rel_emb[wid * NH + lane + 64 * i] * w_attn[lane + 64 * i];
#pragma unroll
    for (int off = 32; off; off >>= 1) p += __shfl_down(p, off);
    if (lane == 0) sRE[wid] = p;
  }
  const float ba = b_attn[0];

  for (int n = 0; n < count; n++) {
    const int gi = start + n;
    const int nd = tm->nodes[gi], cs = tm->cstart[gi], cc = tm->ccount[gi];
    const int ce0 = tm->cens[gi], nic = tm->cens[gi + 1] - ce0;
    if (tid < cc) {
      chl[tid] = tm->echild[cs + tid];
      rll[tid] = tm->erel[cs + tid];
      dcl[tid] = tm->edecay[cs + tid];
    }
    __syncthreads();

    // ---- scores: wave wid handles edges e = wid, wid+4, ... (fp32 w_attn) ----
    for (int e = wid; e < cc; e += 4) {
      const uint16_t* hp = h_bf + ((size_t)(b0 + lb) * NN + chl[e]) * NH + lq * 64;
      float s = 0.f;
#pragma unroll
      for (int v = 0; v < 8; v++) {
        bh8 hv = *(const bh8*)(hp + v * 8);
        const float4 w0 = *(const float4*)(swaf + lq * 64 + v * 8);
        const float4 w1 = *(const float4*)(swaf + lq * 64 + v * 8 + 4);
        s = fmaf(bf2f((uint16_t)hv[0]), w0.x, s);
        s = fmaf(bf2f((uint16_t)hv[1]), w0.y, s);
        s = fmaf(bf2f((uint16_t)hv[2]), w0.z, s);
        s = fmaf(bf2f((uint16_t)hv[3]), w0.w, s);
        s = fmaf(bf2f((uint16_t)hv[4]), w1.x, s);
        s = fmaf(bf2f((uint16_t)hv[5]), w1.y, s);
        s = fmaf(bf2f((uint16_t)hv[6]), w1.z, s);
        s = fmaf(bf2f((uint16_t)hv[7]), w1.w, s);
      }
      s += __shfl_xor(s, 16); s += __shfl_xor(s, 32);
      if (lq == 0) sc[lb * 68 + e] = sRE[rll[e]] + dcl[e] * s + ba;
    }
    __syncthreads();
    if (tid < 16) {  // softmax per batch row; fold decay into weight
      float mx = -1e30f;
      for (int e = 0; e < cc; e++) mx = fmaxf(mx, sc[tid * 68 + e]);
      float ss = 0.f;
      for (int e = 0; e < cc; e++) ss += expf(sc[tid * 68 + e] - mx);
      const float inv = 1.0f / ss;
      for (int e = 0; e < cc; e++) sc[tid * 68 + e] = expf(sc[tid * 68 + e] - mx) * inv * dcl[e];
    }
    __syncthreads();

    // ---- h_sum: thread (b = tid&15, q = tid>>4) covers cols q*16..q*16+15 ----
    {
      const int b = tid & 15, q = tid >> 4;
      float hs[16];
#pragma unroll
      for (int u = 0; u < 16; u++) hs[u] = 0.f;
      for (int e = 0; e < cc; e++) {
        const float w = sc[b * 68 + e];
        const uint16_t* hp = h_bf + ((size_t)(b0 + b) * NN + chl[e]) * NH + q * 16;
        uint4 p0 = *(const uint4*)(hp);
        uint4 p1 = *(const uint4*)(hp + 8);
        const uint16_t* e0 = (const uint16_t*)&p0;
        const uint16_t* e1 = (const uint16_t*)&p1;
#pragma unroll
        for (int u = 0; u < 8; u++) hs[u] = fmaf(bf2f(e0[u]), w, hs[u]);
#pragma unroll
        for (int u = 0; u < 8; u++) hs[8 + u] = fmaf(bf2f(e1[u]), w, hs[8 + u]);
      }
      uint16_t* sub = hsum + (q >> 2) * 1024;
#pragma unroll
      for (int v = 0; v < 8; v++) {
        uint32_t pk = (uint32_t)f2bf(hs[2 * v]) | ((uint32_t)f2bf(hs[2 * v + 1]) << 16);
        const int elem = ((b << 6) + (q & 3) * 16 + 2 * v) ^ ((b & 7) << 3);
        *(uint32_t*)(sub + elem) = pk;
      }
    }

    // ---- csum: wave wid owns cols wid*64..+63 (4 col-frags); direct global ----
    f32x4 csum[4] = {};
    for (int e = 0; e < nic; e++) {
      const int ch = tm->cechild[ce0 + e];
      const int rel = tm->cerel[ce0 + e];
      const float dec = tm->cedec[ce0 + e];
      const uint16_t* hrow = h_bf + ((size_t)(b0 + lb) * NN + ch) * NH;
      const uint16_t* Wr = WfT + (size_t)rel * 65536;
      f32x4 facc[4] = {};
#pragma unroll
      for (int k0 = 0; k0 < 8; k0++) {
        const int kk = k0 * 32 + lq * 8;
        const bh8 af = *(const bh8*)(hrow + kk);
        bh8 bq[4];
#pragma unroll
        for (int j = 0; j < 4; j++)
          bq[j] = *(const bh8*)(Wr + (size_t)(wid * 64 + j * 16 + lb) * 256 + kk);
#pragma unroll
        for (int j = 0; j < 4; j++)
          facc[j] = __builtin_amdgcn_mfma_f32_16x16x32_bf16(af, bq[j], facc[j], 0, 0, 0);
      }
#pragma unroll
      for (int j = 0; j < 4; j++) {
        const int col = wid * 64 + j * 16 + lb;
        const float bfv = b_f[rel * NH + col];
#pragma unroll
        for (int r = 0; r < 4; r++) {
          const int brow = b0 + lq * 4 + r;
          const float cch = c[((size_t)brow * NN + ch) * NH + col];
          csum[j][r] += (dec * facc[j][r] + bfv) * (dec * cch);
        }
      }
    }
    __syncthreads();  // hsum writes visible

    // ---- gates: K=512; A = h_bf[nd] direct | hsum LDS; B = wave's 64 cols ----
    f32x4 ga[3][4] = {};
    const uint16_t* xrow = h_bf + ((size_t)(b0 + lb) * NN + nd) * NH;
#pragma unroll
    for (int k32 = 0; k32 < 16; k32++) {
      const int kk = k32 * 32 + lq * 8;
      bh8 af;
      if (k32 < 8) {
        af = *(const bh8*)(xrow + kk);
      } else {
        const int kx = k32 - 8;
        const int elem = ((lb << 6) + (kx & 1) * 32 + lq * 8) ^ ((lb & 7) << 3);
        af = *(const bh8*)(hsum + (kx >> 1) * 1024 + elem);
      }
#pragma unroll
      for (int g = 0; g < 3; g++) {
#pragma unroll
        for (int j = 0; j < 4; j++) {
          const bh8 bq = *(const bh8*)(WgT + ((size_t)g << 17) +
                                       (size_t)(wid * 64 + j * 16 + lb) * 512 + k32 * 32 + lq * 8);
          ga[g][j] = __builtin_amdgcn_mfma_f32_16x16x32_bf16(af, bq, ga[g][j], 0, 0, 0);
        }
      }
    }
#pragma unroll
    for (int j = 0; j < 4; j++) {
      const int col = wid * 64 + j * 16 + lb;
      const float bi_ = b_i[col], bo_ = b_o[col], bu_ = b_u[col];
#pragma unroll
      for (int r = 0; r < 4; r++) {
        const int brow = b0 + lq * 4 + r;
        const size_t idx = ((size_t)brow * NN + nd) * NH + col;
        const float ig = sigm(ga[0][j][r] + bi_);
        const float og = sigm(ga[1][j][r] + bo_);
        const float ug = tanhf(ga[2][j][r] + bu_);
        const float cn = fmaf(ig, ug, csum[j][r]);
        c[idx] = cn;
        const float hn = og * tanhf(cn);
        h_bf[idx] = f2bf(hn);
        if (nd == 0) out[(size_t)brow * NH + col] = hn;
      }
    }
    __syncthreads();  // node boundary: all global writes/LDS done before reuse
  }
}

// ======================= launch =======================
extern "C" void kernel_launch(void* const* d_in, const int* in_sizes, int n_in,
                              void* d_out, int out_size, void* d_ws, size_t ws_size,
                              hipStream_t stream) {
  (void)in_sizes; (void)n_in; (void)out_size; (void)ws_size;
  const float* nf      = (const float*)d_in[0];
  const float* W_enc   = (const float*)d_in[1];
  const float* b_enc   = (const float*)d_in[2];
  const float* rel_emb = (const float*)d_in[3];
  const float* W_i     = (const float*)d_in[4];
  const float* b_i     = (const float*)d_in[5];
  const float* W_o     = (const float*)d_in[6];
  const float* b_o     = (const float*)d_in[7];
  const float* W_u     = (const float*)d_in[8];
  const float* b_u     = (const float*)d_in[9];
  const float* W_f     = (const float*)d_in[10];
  const float* b_f     = (const float*)d_in[11];
  const float* w_attn  = (const float*)d_in[12];
  const float* b_attn  = (const float*)d_in[13];
  float* out = (float*)d_out;

  static HostTree T;  // rebuilt identically every call (deterministic)
  build_tree_host(T);

  char* ws = (char*)d_ws;
  const size_t OFF_HBF = 32768;
  const size_t SZ_HBF  = (size_t)NB * NN * NH * 2;  // 33.5 MB
  const size_t OFF_WET = OFF_HBF + SZ_HBF;
  const size_t OFF_WFT = OFF_WET + 131072;
  const size_t OFF_WGT = OFF_WFT + 393216;
  const size_t OFF_C   = OFF_WGT + 786432;          // + 67 MB fp32

  TreeMeta* dm = (TreeMeta*)ws;
  uint16_t* h_bf = (uint16_t*)(ws + OFF_HBF);
  uint16_t* WeT = (uint16_t*)(ws + OFF_WET);
  uint16_t* WfT = (uint16_t*)(ws + OFF_WFT);
  uint16_t* WgT = (uint16_t*)(ws + OFF_WGT);
  float* c = (float*)(ws + OFF_C);

  hipMemcpyAsync(dm, &T.meta, sizeof(TreeMeta), hipMemcpyHostToDevice, stream);

  k_prep<<<2560, 256, 0, stream>>>(W_enc, W_f, W_i, W_o, W_u, WeT, WfT, WgT);
  k_enc<<<dim3((NB * NN) / 128, 2), 256, 0, stream>>>(nf, WeT, b_enc, h_bf);

  int l = 0;
  while (l < T.n_levels) {
    if (T.level_M[l] >= TH_TAIL) {
      const int Mfull = T.level_M[l];
      for (int c0 = 0; c0 < Mfull; c0 += 128) {
        const int Mc = (Mfull - c0) < 128 ? (Mfull - c0) : 128;
        k_lvl<<<dim3(2 * Mc, 4), 256, 0, stream>>>(h_bf, c, WfT, WgT,
            b_f, b_i, b_o, b_u, rel_emb, w_attn, b_attn, out, dm,
            T.level_off[l] + c0);
      }
      l++;
    } else {
      int j = l, cnt = 0;
      while (j < T.n_levels && T.level_M[j] < TH_TAIL) { cnt += T.level_M[j]; j++; }
      k_tail<<<dim3(8), 256, 0, stream>>>(h_bf, c, WfT, WgT,
          b_f, b_i, b_o, b_u, rel_emb, w_attn, b_attn, out, dm,
          T.level_off[l], cnt);
      l = j;
    }
  }
}

// Round 10
// 682.033 us; speedup vs baseline: 2.2850x; 2.2850x over previous
//
#include <hip/hip_runtime.h>
#include <stdint.h>
#include <string.h>
#include <math.h>

#define NB 128   // batch
#define NN 512   // nodes
#define NH 256   // hidden
#define NR 3
#define TH_TINY 8

typedef __attribute__((ext_vector_type(8))) short bh8;   // 8 x bf16
typedef __attribute__((ext_vector_type(4))) float f32x4;

// ======================= numpy RNG reproduction (host) =======================
struct Pcg {
  __uint128_t state, inc;
  bool has32; uint32_t buf32;
};

static const __uint128_t PCG_MULT =
    (((__uint128_t)2549297995355413924ULL) << 64) | 4865540595714422341ULL;

static inline uint64_t pcg_next64(Pcg& s) {
  s.state = s.state * PCG_MULT + s.inc;
  uint64_t hi = (uint64_t)(s.state >> 64), lo = (uint64_t)s.state;
  uint64_t x = hi ^ lo;
  unsigned rot = (unsigned)(s.state >> 122) & 63u;
  return (x >> rot) | (x << ((64u - rot) & 63u));
}
static inline uint32_t pcg_next32(Pcg& s) {
  if (s.has32) { s.has32 = false; return s.buf32; }
  uint64_t n = pcg_next64(s);
  s.has32 = true; s.buf32 = (uint32_t)(n >> 32);
  return (uint32_t)n;
}
static inline uint64_t pcg_bounded(Pcg& s, uint64_t high) {
  uint64_t rng = high - 1;
  if (rng == 0) return 0;
  uint32_t rng_excl = (uint32_t)rng + 1u;
  uint64_t m = (uint64_t)pcg_next32(s) * (uint64_t)rng_excl;
  uint32_t leftover = (uint32_t)m;
  if (leftover < rng_excl) {
    uint32_t threshold = (uint32_t)((0xFFFFFFFFu - (uint32_t)rng) % rng_excl);
    while (leftover < threshold) {
      m = (uint64_t)pcg_next32(s) * (uint64_t)rng_excl;
      leftover = (uint32_t)m;
    }
  }
  return m >> 32;
}
static inline double pcg_double(Pcg& s) {
  return (double)(pcg_next64(s) >> 11) * (1.0 / 9007199254740992.0);
}

static void pcg_seed0(Pcg& s) {
  uint32_t pool[4];
  uint32_t hc = 0x43b0d7e5u;
  auto hashmix = [&hc](uint32_t v) -> uint32_t {
    v ^= hc; hc *= 0x931e8875u; v *= hc; v ^= v >> 16; return v;
  };
  auto mix = [](uint32_t x, uint32_t y) -> uint32_t {
    uint32_t r = 0xca01f9ddu * x - 0x4973f715u * y; r ^= r >> 16; return r;
  };
  for (int i = 0; i < 4; i++) pool[i] = hashmix(0u);
  for (int src = 0; src < 4; src++)
    for (int dst = 0; dst < 4; dst++)
      if (src != dst) pool[dst] = mix(pool[dst], hashmix(pool[src]));
  uint32_t gs[8]; uint32_t hb = 0x8b51f9ddu;
  for (int i = 0; i < 8; i++) {
    uint32_t dv = pool[i & 3];
    dv ^= hb; hb *= 0x58f38dedu; dv *= hb; dv ^= dv >> 16;
    gs[i] = dv;
  }
  uint64_t w0 = (uint64_t)gs[0] | ((uint64_t)gs[1] << 32);
  uint64_t w1 = (uint64_t)gs[2] | ((uint64_t)gs[3] << 32);
  uint64_t w2 = (uint64_t)gs[4] | ((uint64_t)gs[5] << 32);
  uint64_t w3 = (uint64_t)gs[6] | ((uint64_t)gs[7] << 32);
  __uint128_t initstate = (((__uint128_t)w0) << 64) | w1;
  __uint128_t initseq   = (((__uint128_t)w2) << 64) | w3;
  s.state = 0;
  s.inc = (initseq << 1) | 1;
  s.state = s.state * PCG_MULT + s.inc;
  s.state += initstate;
  s.state = s.state * PCG_MULT + s.inc;
  s.has32 = false; s.buf32 = 0;
}

// ======================= tree build (host) =======================
struct TreeMeta {
  int nodes[512];    // internal nodes, level-ordered (deepest first)
  int cstart[512];
  int ccount[512];
  int echild[512];   // all-children edges, node-grouped
  int erel[512];
  float edecay[512];
  int cechild[512];  // csum edges (internal children only), node-grouped
  int cerel[512];
  float cedec[512];
  int cens[513];     // per meta-node index -> first csum edge (+ sentinel)
};
struct HostTree {
  TreeMeta meta;
  int n_levels;
  int level_off[520];
  int level_M[520];
};

static void build_tree_host(HostTree& T) {
  Pcg st; pcg_seed0(st);
  int parent[NN], depth[NN], rel[NN];
  unsigned char virt[NN];
  parent[0] = 0; depth[0] = 0;
  for (int i = 1; i < NN; i++) parent[i] = (int)pcg_bounded(st, (uint64_t)i);
  for (int i = 1; i < NN; i++) depth[i] = depth[parent[i]] + 1;
  for (int i = 0; i < NN; i++) rel[i] = (int)pcg_bounded(st, (uint64_t)NR);
  for (int i = 0; i < NN; i++) virt[i] = (pcg_double(st) < 0.1) ? 1 : 0;

  int childcnt[NN]; memset(childcnt, 0, sizeof(childcnt));
  for (int i = 1; i < NN; i++) childcnt[parent[i]]++;
  int maxd = 0;
  for (int i = 0; i < NN; i++) if (depth[i] > maxd) maxd = depth[i];

  int ni = 0, ne = 0, nec = 0;
  T.n_levels = 0;
  for (int d = maxd; d >= 0; d--) {
    int mstart = ni;
    for (int n = 0; n < NN; n++) {
      if (depth[n] == d && childcnt[n] > 0) {
        T.meta.nodes[ni] = n;
        T.meta.cstart[ni] = ne;
        T.meta.ccount[ni] = childcnt[n];
        T.meta.cens[ni] = nec;
        for (int i2 = 1; i2 < NN; i2++) {
          if (parent[i2] == n) {
            T.meta.echild[ne] = i2;
            T.meta.erel[ne] = rel[i2];
            T.meta.edecay[ne] = virt[i2] ? 0.7f : 1.0f;
            ne++;
            if (childcnt[i2] > 0) {  // leaf children contribute exactly 0 to c_sum
              T.meta.cechild[nec] = i2;
              T.meta.cerel[nec] = rel[i2];
              T.meta.cedec[nec] = virt[i2] ? 0.7f : 1.0f;
              nec++;
            }
          }
        }
        ni++;
      }
    }
    if (ni > mstart) {
      T.level_off[T.n_levels] = mstart;
      T.level_M[T.n_levels] = ni - mstart;
      T.n_levels++;
    }
  }
  T.meta.cens[ni] = nec;
}

// ======================= device helpers =======================
__device__ __forceinline__ uint16_t f2bf(float f) {
  uint32_t u = __float_as_uint(f);
  return (uint16_t)((u + 0x7fffu + ((u >> 16) & 1u)) >> 16);
}
__device__ __forceinline__ float bf2f(uint16_t b) {
  return __uint_as_float(((uint32_t)b) << 16);
}
__device__ __forceinline__ float sigm(float x) {
  return 1.f / (1.f + expf(-x));
}

// Stage rows x 64 bf16 tile into LDS with XOR swizzle: elem ^= (row&7)<<3
__device__ __forceinline__ void stage_bf16(uint16_t* __restrict__ sm,
    const uint16_t* __restrict__ src, int stride, int rows) {
  const int chunks = rows << 3;
  for (int cch = threadIdx.x; cch < chunks; cch += 256) {
    const int row = cch >> 3, k = (cch & 7) << 3;
    uint4 v = *(const uint4*)(src + (size_t)row * stride + k);
    *(uint4*)(sm + (((row << 6) + k) ^ ((row & 7) << 3))) = v;
  }
}
__device__ __forceinline__ void stage_f32(uint16_t* __restrict__ sm,
    const float* __restrict__ src, int stride, int rows) {
  const int chunks = rows << 3;
  for (int cch = threadIdx.x; cch < chunks; cch += 256) {
    const int row = cch >> 3, k = (cch & 7) << 3;
    const float* p = src + (size_t)row * stride + k;
    float4 a = *(const float4*)p, b = *(const float4*)(p + 4);
    uint4 w;
    w.x = (uint32_t)f2bf(a.x) | ((uint32_t)f2bf(a.y) << 16);
    w.y = (uint32_t)f2bf(a.z) | ((uint32_t)f2bf(a.w) << 16);
    w.z = (uint32_t)f2bf(b.x) | ((uint32_t)f2bf(b.y) << 16);
    w.w = (uint32_t)f2bf(b.z) | ((uint32_t)f2bf(b.w) << 16);
    *(uint4*)(sm + (((row << 6) + k) ^ ((row & 7) << 3))) = w;
  }
}
__device__ __forceinline__ bh8 fld(const uint16_t* __restrict__ sm, int row, int k) {
  return *(const bh8*)(sm + (((row << 6) + k) ^ ((row & 7) << 3)));
}

// ======================= weight prep: transpose + bf16 =======================
__global__ __launch_bounds__(256) void k_prep(const float* __restrict__ We,
    const float* __restrict__ Wf, const float* __restrict__ Wi,
    const float* __restrict__ Wo, const float* __restrict__ Wu,
    uint16_t* __restrict__ WeT, uint16_t* __restrict__ WfT,
    uint16_t* __restrict__ WgT) {
  const int i = blockIdx.x * 256 + threadIdx.x;
  if (i < 65536) {
    const int n = i >> 8, k = i & 255;
    WeT[i] = f2bf(We[k * 256 + n]);
  }
  const int i2 = i - 65536;
  if (i2 >= 0 && i2 < 196608) {
    const int r = i2 >> 16, rem = i2 & 65535, n = rem >> 8, k = rem & 255;
    WfT[i2] = f2bf(Wf[r * 65536 + k * 256 + n]);
  }
  const int i3 = i - 262144;
  if (i3 >= 0 && i3 < 393216) {
    const int g = i3 >> 17, rem = i3 & 131071, n = rem >> 9, k = rem & 511;
    const float* S = (g == 0) ? Wi : (g == 1) ? Wo : Wu;
    WgT[i3] = f2bf(S[k * 256 + n]);
  }
}

// ======================= encoder: h_bf = bf16(nf @ W_enc + b) =======================
__global__ __launch_bounds__(256) void k_enc(const float* __restrict__ nf,
    const uint16_t* __restrict__ WeT, const float* __restrict__ b_enc,
    uint16_t* __restrict__ h_bf) {
  __shared__ __align__(16) uint16_t smA[128 * 64];
  __shared__ __align__(16) uint16_t smB[128 * 64];
  const int bm = blockIdx.x * 128, bn = blockIdx.y * 128;
  const int tid = threadIdx.x, wid = tid >> 6, lane = tid & 63;
  const int wr = wid >> 1, wc2 = wid & 1, lr = lane & 15, lk = (lane >> 4) << 3;
  f32x4 acc[4][4] = {};
  for (int k0 = 0; k0 < 256; k0 += 64) {
    __syncthreads();
    stage_f32(smA, nf + (size_t)bm * NH + k0, NH, 128);
    stage_bf16(smB, WeT + (size_t)bn * 256 + k0, 256, 128);
    __syncthreads();
#pragma unroll
    for (int ks = 0; ks < 2; ks++) {
      bh8 af[4], bfr[4];
#pragma unroll
      for (int i = 0; i < 4; i++) af[i] = fld(smA, wr * 64 + i * 16 + lr, ks * 32 + lk);
#pragma unroll
      for (int j = 0; j < 4; j++) bfr[j] = fld(smB, wc2 * 64 + j * 16 + lr, ks * 32 + lk);
#pragma unroll
      for (int i = 0; i < 4; i++)
#pragma unroll
        for (int j = 0; j < 4; j++)
          acc[i][j] = __builtin_amdgcn_mfma_f32_16x16x32_bf16(af[i], bfr[j], acc[i][j], 0, 0, 0);
    }
  }
#pragma unroll
  for (int i = 0; i < 4; i++) {
#pragma unroll
    for (int j = 0; j < 4; j++) {
      const int col = bn + wc2 * 64 + j * 16 + (lane & 15);
      const float be = b_enc[col];
#pragma unroll
      for (int r = 0; r < 4; r++) {
        const int row = bm + wr * 64 + i * 16 + (lane >> 4) * 4 + r;
        h_bf[(size_t)row * NH + col] = f2bf(acc[i][j][r] + be);
      }
    }
  }
}

// ======================= fused per-level kernel, col-sliced (big levels) =======================
__global__ __launch_bounds__(256) void k_lvl(
    uint16_t* h_bf, float* c,
    const uint16_t* __restrict__ WfT, const uint16_t* __restrict__ WgT,
    const float* __restrict__ b_f, const float* __restrict__ b_i,
    const float* __restrict__ b_o, const float* __restrict__ b_u,
    const float* __restrict__ rel_emb, const float* __restrict__ w_attn,
    const float* __restrict__ b_attn, float* __restrict__ out,
    const TreeMeta* __restrict__ tm, int nb) {
  __shared__ float sc[64 * 65];                           // 16.6 KB
  __shared__ float swa[256];
  __shared__ float sRE[3];
  __shared__ int chl[64]; __shared__ int rll[64]; __shared__ float dcl[64];
  __shared__ __align__(16) uint16_t hsum[4 * 4096];       // 32 KB (64 x 256)

  const int bx = blockIdx.x, mloc = bx >> 1, b0 = (bx & 1) * 64;
  const int cslice = blockIdx.y * 64;
  const int gi = nb + mloc;
  const int nd = tm->nodes[gi], cs = tm->cstart[gi], cc = tm->ccount[gi];
  const int ce0 = tm->cens[gi], nic = tm->cens[gi + 1] - ce0;
  const int tid = threadIdx.x, wid = tid >> 6, lane = tid & 63;
  const int lr2 = lane & 15, hi4 = (lane >> 4), lk = hi4 << 3;
  const int colw = cslice + wid * 16 + lr2;  // this lane's output column

  if (tid < cc) {
    chl[tid] = tm->echild[cs + tid];
    rll[tid] = tm->erel[cs + tid];
    dcl[tid] = tm->edecay[cs + tid];
  }
  swa[tid] = w_attn[tid];
  if (wid < 3) {  // sRE[r] = rel_emb[r] . w_attn
    float p = 0.f;
#pragma unroll
    for (int i = 0; i < 4; i++) p += rel_emb[wid * NH + lane + 64 * i] * w_attn[lane + 64 * i];
#pragma unroll
    for (int off = 32; off; off >>= 1) p += __shfl_down(p, off);
    if (lane == 0) sRE[wid] = p;
  }
  __syncthreads();

  // ---- scores (full 256-dim) ----
  const int sb = tid >> 2, sq = tid & 3;  // 4 threads per batch row
  const float ba = b_attn[0];
  for (int e = 0; e < cc; e++) {
    const uint16_t* hp = h_bf + ((size_t)(b0 + sb) * NN + chl[e]) * NH + sq * 64;
    float s = 0.f;
#pragma unroll
    for (int v = 0; v < 8; v++) {
      uint4 pk = *(const uint4*)(hp + v * 8);
      const uint16_t* pe = (const uint16_t*)&pk;
#pragma unroll
      for (int q = 0; q < 8; q++) s = fmaf(bf2f(pe[q]), swa[sq * 64 + v * 8 + q], s);
    }
    s += __shfl_xor(s, 1); s += __shfl_xor(s, 2);
    if (sq == 0) sc[sb * 65 + e] = sRE[rll[e]] + dcl[e] * s + ba;
  }
  __syncthreads();
  // ---- softmax per batch row; fold decay into weight ----
  if (tid < 64) {
    float mx = -1e30f;
    for (int e = 0; e < cc; e++) mx = fmaxf(mx, sc[tid * 65 + e]);
    float ss = 0.f;
    for (int e = 0; e < cc; e++) ss += expf(sc[tid * 65 + e] - mx);
    const float inv = 1.0f / ss;
    for (int e = 0; e < cc; e++) sc[tid * 65 + e] = expf(sc[tid * 65 + e] - mx) * inv * dcl[e];
  }
  __syncthreads();

  // ---- h_sum (full 256-dim) -> LDS ----
  {
    float hs[64];
#pragma unroll
    for (int v = 0; v < 64; v++) hs[v] = 0.f;
    for (int e = 0; e < cc; e++) {
      const float w = sc[sb * 65 + e];
      const uint16_t* hp = h_bf + ((size_t)(b0 + sb) * NN + chl[e]) * NH + sq * 64;
#pragma unroll
      for (int v = 0; v < 8; v++) {
        uint4 pk = *(const uint4*)(hp + v * 8);
        const uint16_t* pe = (const uint16_t*)&pk;
#pragma unroll
        for (int q = 0; q < 8; q++) hs[v * 8 + q] = fmaf(bf2f(pe[q]), w, hs[v * 8 + q]);
      }
    }
    uint16_t* sub = hsum + sq * 4096;
#pragma unroll
    for (int v = 0; v < 32; v++) {
      uint32_t pk = (uint32_t)f2bf(hs[2 * v]) | ((uint32_t)f2bf(hs[2 * v + 1]) << 16);
      const int elem = ((sb << 6) + 2 * v) ^ ((sb & 7) << 3);
      *(uint32_t*)(sub + elem) = pk;
    }
  }

  // ---- csum for this 64-col slice: direct-global MFMA, no barriers ----
  f32x4 csum[4] = {};
  for (int e = 0; e < nic; e++) {
    const int ch = tm->cechild[ce0 + e];
    const int rel = tm->cerel[ce0 + e];
    const float dec = tm->cedec[ce0 + e];
    const uint16_t* Wr = WfT + (size_t)rel * 65536 + (size_t)colw * 256;
    f32x4 facc[4] = {};
#pragma unroll
    for (int k0 = 0; k0 < 8; k0++) {
      const int kk = k0 * 32 + lk;
      bh8 af[4];
#pragma unroll
      for (int i = 0; i < 4; i++)
        af[i] = *(const bh8*)(h_bf + ((size_t)(b0 + i * 16 + lr2) * NN + ch) * NH + kk);
      const bh8 bq = *(const bh8*)(Wr + kk);
#pragma unroll
      for (int i = 0; i < 4; i++)
        facc[i] = __builtin_amdgcn_mfma_f32_16x16x32_bf16(af[i], bq, facc[i], 0, 0, 0);
    }
    const float bfv = b_f[rel * NH + colw];
#pragma unroll
    for (int i = 0; i < 4; i++) {
#pragma unroll
      for (int r = 0; r < 4; r++) {
        const int brow = b0 + i * 16 + hi4 * 4 + r;
        const float cch = c[((size_t)brow * NN + ch) * NH + colw];
        csum[i][r] += (dec * facc[i][r] + bfv) * (dec * cch);
      }
    }
  }
  __syncthreads();  // hsum writes visible before gates reads

  // ---- gates GEMM (K=512): A = h_bf[nd] direct | hsum LDS; B = col slice ----
  f32x4 ga[3][4] = {};
#pragma unroll
  for (int k32 = 0; k32 < 16; k32++) {
    const int kk = k32 * 32 + lk;
    bh8 af[4], bq[3];
    if (k32 < 8) {
#pragma unroll
      for (int i = 0; i < 4; i++)
        af[i] = *(const bh8*)(h_bf + ((size_t)(b0 + i * 16 + lr2) * NN + nd) * NH + kk);
    } else {
      const int kx = k32 - 8;
#pragma unroll
      for (int i = 0; i < 4; i++)
        af[i] = fld(hsum + (kx >> 1) * 4096, i * 16 + lr2, (kx & 1) * 32 + lk);
    }
#pragma unroll
    for (int g = 0; g < 3; g++)
      bq[g] = *(const bh8*)(WgT + ((size_t)g << 17) + (size_t)colw * 512 + kk);
#pragma unroll
    for (int g = 0; g < 3; g++)
#pragma unroll
      for (int i = 0; i < 4; i++)
        ga[g][i] = __builtin_amdgcn_mfma_f32_16x16x32_bf16(af[i], bq[g], ga[g][i], 0, 0, 0);
  }

  const float bi_ = b_i[colw], bo_ = b_o[colw], bu_ = b_u[colw];
#pragma unroll
  for (int i = 0; i < 4; i++) {
#pragma unroll
    for (int r = 0; r < 4; r++) {
      const int brow = b0 + i * 16 + hi4 * 4 + r;
      const size_t idx = ((size_t)brow * NN + nd) * NH + colw;
      const float ig = sigm(ga[0][i][r] + bi_);
      const float og = sigm(ga[1][i][r] + bo_);
      const float ug = tanhf(ga[2][i][r] + bu_);
      const float cn = fmaf(ig, ug, csum[i][r]);
      c[idx] = cn;
      const float hn = og * tanhf(cn);
      h_bf[idx] = f2bf(hn);
      if (nd == 0) out[(size_t)brow * NH + colw] = hn;
    }
  }
}

// ======================= tiny-level kernel: fine col-tiled, max in-flight =======================
// grid = (16 col-slices of 16 cols, 2M batch-half x node). block = 64 rows x
// 16 cols, 4 waves (wave = 16x16 MFMA tile, wave w owns rows b0+w*16..+15).
// grid.x fastest => all batch/node blocks of col-slice j land on XCD j%8,
// sharing the weight lines in one L2. No atomics, no memset.
__global__ __launch_bounds__(256) void k_tiny(
    uint16_t* h_bf, float* c,
    const uint16_t* __restrict__ WfT, const uint16_t* __restrict__ WgT,
    const float* __restrict__ b_f, const float* __restrict__ b_i,
    const float* __restrict__ b_o, const float* __restrict__ b_u,
    const float* __restrict__ rel_emb, const float* __restrict__ w_attn,
    const float* __restrict__ b_attn, float* __restrict__ out,
    const TreeMeta* __restrict__ tm, int nb) {
  __shared__ float sc[64 * 65];                           // 16.6 KB
  __shared__ float swa[256];
  __shared__ float sRE[3];
  __shared__ int chl[64]; __shared__ int rll[64]; __shared__ float dcl[64];
  __shared__ __align__(16) uint16_t hsum[4 * 4096];       // 32 KB (64 x 256)

  const int c0 = blockIdx.x * 16;
  const int mloc = blockIdx.y >> 1, b0 = (blockIdx.y & 1) * 64;
  const int gi = nb + mloc;
  const int nd = tm->nodes[gi], cs = tm->cstart[gi], cc = tm->ccount[gi];
  const int ce0 = tm->cens[gi], nic = tm->cens[gi + 1] - ce0;
  const int tid = threadIdx.x, wid = tid >> 6, lane = tid & 63;
  const int lb = lane & 15, lq = lane >> 4;
  const int colw = c0 + lb;           // lane's output column
  const int wrow = b0 + wid * 16;     // wave's 16-row base

  if (tid < cc) {
    chl[tid] = tm->echild[cs + tid];
    rll[tid] = tm->erel[cs + tid];
    dcl[tid] = tm->edecay[cs + tid];
  }
  swa[tid] = w_attn[tid];
  if (wid < 3) {  // sRE[r] = rel_emb[r] . w_attn
    float p = 0.f;
#pragma unroll
    for (int i = 0; i < 4; i++) p += rel_emb[wid * NH + lane + 64 * i] * w_attn[lane + 64 * i];
#pragma unroll
    for (int off = 32; off; off >>= 1) p += __shfl_down(p, off);
    if (lane == 0) sRE[wid] = p;
  }
  __syncthreads();

  // ---- scores (full 256-dim, 64 rows) ----
  const int sb = tid >> 2, sq = tid & 3;
  const float ba = b_attn[0];
  for (int e = 0; e < cc; e++) {
    const uint16_t* hp = h_bf + ((size_t)(b0 + sb) * NN + chl[e]) * NH + sq * 64;
    float s = 0.f;
#pragma unroll
    for (int v = 0; v < 8; v++) {
      uint4 pk = *(const uint4*)(hp + v * 8);
      const uint16_t* pe = (const uint16_t*)&pk;
#pragma unroll
      for (int q = 0; q < 8; q++) s = fmaf(bf2f(pe[q]), swa[sq * 64 + v * 8 + q], s);
    }
    s += __shfl_xor(s, 1); s += __shfl_xor(s, 2);
    if (sq == 0) sc[sb * 65 + e] = sRE[rll[e]] + dcl[e] * s + ba;
  }
  __syncthreads();
  if (tid < 64) {  // softmax; fold decay
    float mx = -1e30f;
    for (int e = 0; e < cc; e++) mx = fmaxf(mx, sc[tid * 65 + e]);
    float ss = 0.f;
    for (int e = 0; e < cc; e++) ss += expf(sc[tid * 65 + e] - mx);
    const float inv = 1.0f / ss;
    for (int e = 0; e < cc; e++) sc[tid * 65 + e] = expf(sc[tid * 65 + e] - mx) * inv * dcl[e];
  }
  __syncthreads();

  // ---- h_sum (full 256-dim) -> LDS ----
  {
    float hs[64];
#pragma unroll
    for (int v = 0; v < 64; v++) hs[v] = 0.f;
    for (int e = 0; e < cc; e++) {
      const float w = sc[sb * 65 + e];
      const uint16_t* hp = h_bf + ((size_t)(b0 + sb) * NN + chl[e]) * NH + sq * 64;
#pragma unroll
      for (int v = 0; v < 8; v++) {
        uint4 pk = *(const uint4*)(hp + v * 8);
        const uint16_t* pe = (const uint16_t*)&pk;
#pragma unroll
        for (int q = 0; q < 8; q++) hs[v * 8 + q] = fmaf(bf2f(pe[q]), w, hs[v * 8 + q]);
      }
    }
    uint16_t* sub = hsum + sq * 4096;
#pragma unroll
    for (int v = 0; v < 32; v++) {
      uint32_t pk = (uint32_t)f2bf(hs[2 * v]) | ((uint32_t)f2bf(hs[2 * v + 1]) << 16);
      const int elem = ((sb << 6) + 2 * v) ^ ((sb & 7) << 3);
      *(uint32_t*)(sub + elem) = pk;
    }
  }

  // ---- csum: wave's 16 rows x block's 16 cols; direct-global MFMA ----
  f32x4 csum = {};
  for (int e = 0; e < nic; e++) {
    const int ch = tm->cechild[ce0 + e];
    const int rel = tm->cerel[ce0 + e];
    const float dec = tm->cedec[ce0 + e];
    const uint16_t* Wr = WfT + (size_t)rel * 65536 + (size_t)colw * 256;
    f32x4 facc = {};
#pragma unroll
    for (int k0 = 0; k0 < 8; k0++) {
      const int kk = k0 * 32 + lq * 8;
      const bh8 af = *(const bh8*)(h_bf + ((size_t)(wrow + lb) * NN + ch) * NH + kk);
      const bh8 bq = *(const bh8*)(Wr + kk);
      facc = __builtin_amdgcn_mfma_f32_16x16x32_bf16(af, bq, facc, 0, 0, 0);
    }
    const float bfv = b_f[rel * NH + colw];
#pragma unroll
    for (int r = 0; r < 4; r++) {
      const int brow = wrow + lq * 4 + r;
      const float cch = c[((size_t)brow * NN + ch) * NH + colw];
      csum[r] += (dec * facc[r] + bfv) * (dec * cch);
    }
  }
  __syncthreads();  // hsum visible

  // ---- gates (K=512): A = h_bf[nd] direct | hsum LDS; B = 16-col slice ----
  f32x4 ga[3] = {};
#pragma unroll
  for (int k32 = 0; k32 < 16; k32++) {
    const int kk = k32 * 32 + lq * 8;
    bh8 af;
    if (k32 < 8) {
      af = *(const bh8*)(h_bf + ((size_t)(wrow + lb) * NN + nd) * NH + kk);
    } else {
      const int kx = k32 - 8;
      af = fld(hsum + (kx >> 1) * 4096, wid * 16 + lb, (kx & 1) * 32 + lq * 8);
    }
#pragma unroll
    for (int g = 0; g < 3; g++) {
      const bh8 bq = *(const bh8*)(WgT + ((size_t)g << 17) + (size_t)colw * 512 + kk);
      ga[g] = __builtin_amdgcn_mfma_f32_16x16x32_bf16(af, bq, ga[g], 0, 0, 0);
    }
  }

  const float bi_ = b_i[colw], bo_ = b_o[colw], bu_ = b_u[colw];
#pragma unroll
  for (int r = 0; r < 4; r++) {
    const int brow = wrow + lq * 4 + r;
    const size_t idx = ((size_t)brow * NN + nd) * NH + colw;
    const float ig = sigm(ga[0][r] + bi_);
    const float og = sigm(ga[1][r] + bo_);
    const float ug = tanhf(ga[2][r] + bu_);
    const float cn = fmaf(ig, ug, csum[r]);
    c[idx] = cn;
    const float hn = og * tanhf(cn);
    h_bf[idx] = f2bf(hn);
    if (nd == 0) out[(size_t)brow * NH + colw] = hn;
  }
}

// ======================= launch =======================
extern "C" void kernel_launch(void* const* d_in, const int* in_sizes, int n_in,
                              void* d_out, int out_size, void* d_ws, size_t ws_size,
                              hipStream_t stream) {
  (void)in_sizes; (void)n_in; (void)out_size; (void)ws_size;
  const float* nf      = (const float*)d_in[0];
  const float* W_enc   = (const float*)d_in[1];
  const float* b_enc   = (const float*)d_in[2];
  const float* rel_emb = (const float*)d_in[3];
  const float* W_i     = (const float*)d_in[4];
  const float* b_i     = (const float*)d_in[5];
  const float* W_o     = (const float*)d_in[6];
  const float* b_o     = (const float*)d_in[7];
  const float* W_u     = (const float*)d_in[8];
  const float* b_u     = (const float*)d_in[9];
  const float* W_f     = (const float*)d_in[10];
  const float* b_f     = (const float*)d_in[11];
  const float* w_attn  = (const float*)d_in[12];
  const float* b_attn  = (const float*)d_in[13];
  float* out = (float*)d_out;

  static HostTree T;  // rebuilt identically every call (deterministic)
  build_tree_host(T);

  char* ws = (char*)d_ws;
  const size_t OFF_HBF = 32768;
  const size_t SZ_HBF  = (size_t)NB * NN * NH * 2;  // 33.5 MB
  const size_t OFF_WET = OFF_HBF + SZ_HBF;
  const size_t OFF_WFT = OFF_WET + 131072;
  const size_t OFF_WGT = OFF_WFT + 393216;
  const size_t OFF_C   = OFF_WGT + 786432;          // + 67 MB fp32

  TreeMeta* dm = (TreeMeta*)ws;
  uint16_t* h_bf = (uint16_t*)(ws + OFF_HBF);
  uint16_t* WeT = (uint16_t*)(ws + OFF_WET);
  uint16_t* WfT = (uint16_t*)(ws + OFF_WFT);
  uint16_t* WgT = (uint16_t*)(ws + OFF_WGT);
  float* c = (float*)(ws + OFF_C);

  hipMemcpyAsync(dm, &T.meta, sizeof(TreeMeta), hipMemcpyHostToDevice, stream);

  k_prep<<<2560, 256, 0, stream>>>(W_enc, W_f, W_i, W_o, W_u, WeT, WfT, WgT);
  k_enc<<<dim3((NB * NN) / 128, 2), 256, 0, stream>>>(nf, WeT, b_enc, h_bf);

  for (int l = 0; l < T.n_levels; l++) {
    const int Mfull = T.level_M[l];
    if (Mfull >= TH_TINY) {
      for (int c0 = 0; c0 < Mfull; c0 += 128) {
        const int Mc = (Mfull - c0) < 128 ? (Mfull - c0) : 128;
        k_lvl<<<dim3(2 * Mc, 4), 256, 0, stream>>>(h_bf, c, WfT, WgT,
            b_f, b_i, b_o, b_u, rel_emb, w_attn, b_attn, out, dm,
            T.level_off[l] + c0);
      }
    } else {
      k_tiny<<<dim3(16, 2 * Mfull), 256, 0, stream>>>(h_bf, c, WfT, WgT,
          b_f, b_i, b_o, b_u, rel_emb, w_attn, b_attn, out, dm,
          T.level_off[l]);
    }
  }
}

// Round 12
// 612.860 us; speedup vs baseline: 2.5429x; 1.1129x over previous
//
#include <hip/hip_runtime.h>
#include <stdint.h>
#include <string.h>
#include <math.h>

#define NB 128   // batch
#define NN 512   // nodes
#define NH 256   // hidden
#define NR 3
#define TH_TINY 24

typedef __attribute__((ext_vector_type(8))) short bh8;   // 8 x bf16
typedef __attribute__((ext_vector_type(4))) float f32x4;

// ======================= numpy RNG reproduction (host) =======================
struct Pcg {
  __uint128_t state, inc;
  bool has32; uint32_t buf32;
};

static const __uint128_t PCG_MULT =
    (((__uint128_t)2549297995355413924ULL) << 64) | 4865540595714422341ULL;

static inline uint64_t pcg_next64(Pcg& s) {
  s.state = s.state * PCG_MULT + s.inc;
  uint64_t hi = (uint64_t)(s.state >> 64), lo = (uint64_t)s.state;
  uint64_t x = hi ^ lo;
  unsigned rot = (unsigned)(s.state >> 122) & 63u;
  return (x >> rot) | (x << ((64u - rot) & 63u));
}
static inline uint32_t pcg_next32(Pcg& s) {
  if (s.has32) { s.has32 = false; return s.buf32; }
  uint64_t n = pcg_next64(s);
  s.has32 = true; s.buf32 = (uint32_t)(n >> 32);
  return (uint32_t)n;
}
static inline uint64_t pcg_bounded(Pcg& s, uint64_t high) {
  uint64_t rng = high - 1;
  if (rng == 0) return 0;
  uint32_t rng_excl = (uint32_t)rng + 1u;
  uint64_t m = (uint64_t)pcg_next32(s) * (uint64_t)rng_excl;
  uint32_t leftover = (uint32_t)m;
  if (leftover < rng_excl) {
    uint32_t threshold = (uint32_t)((0xFFFFFFFFu - (uint32_t)rng) % rng_excl);
    while (leftover < threshold) {
      m = (uint64_t)pcg_next32(s) * (uint64_t)rng_excl;
      leftover = (uint32_t)m;
    }
  }
  return m >> 32;
}
static inline double pcg_double(Pcg& s) {
  return (double)(pcg_next64(s) >> 11) * (1.0 / 9007199254740992.0);
}

static void pcg_seed0(Pcg& s) {
  uint32_t pool[4];
  uint32_t hc = 0x43b0d7e5u;
  auto hashmix = [&hc](uint32_t v) -> uint32_t {
    v ^= hc; hc *= 0x931e8875u; v *= hc; v ^= v >> 16; return v;
  };
  auto mix = [](uint32_t x, uint32_t y) -> uint32_t {
    uint32_t r = 0xca01f9ddu * x - 0x4973f715u * y; r ^= r >> 16; return r;
  };
  for (int i = 0; i < 4; i++) pool[i] = hashmix(0u);
  for (int src = 0; src < 4; src++)
    for (int dst = 0; dst < 4; dst++)
      if (src != dst) pool[dst] = mix(pool[dst], hashmix(pool[src]));
  uint32_t gs[8]; uint32_t hb = 0x8b51f9ddu;
  for (int i = 0; i < 8; i++) {
    uint32_t dv = pool[i & 3];
    dv ^= hb; hb *= 0x58f38dedu; dv *= hb; dv ^= dv >> 16;
    gs[i] = dv;
  }
  uint64_t w0 = (uint64_t)gs[0] | ((uint64_t)gs[1] << 32);
  uint64_t w1 = (uint64_t)gs[2] | ((uint64_t)gs[3] << 32);
  uint64_t w2 = (uint64_t)gs[4] | ((uint64_t)gs[5] << 32);
  uint64_t w3 = (uint64_t)gs[6] | ((uint64_t)gs[7] << 32);
  __uint128_t initstate = (((__uint128_t)w0) << 64) | w1;
  __uint128_t initseq   = (((__uint128_t)w2) << 64) | w3;
  s.state = 0;
  s.inc = (initseq << 1) | 1;
  s.state = s.state * PCG_MULT + s.inc;
  s.state += initstate;
  s.state = s.state * PCG_MULT + s.inc;
  s.has32 = false; s.buf32 = 0;
}

// ======================= tree build (host) =======================
struct TreeMeta {
  int nodes[512];    // internal nodes, level-ordered (deepest first)
  int cstart[512];
  int ccount[512];
  int echild[512];   // all-children edges, node-grouped
  int erel[512];
  float edecay[512];
  int cechild[512];  // csum edges (internal children only), node-grouped
  int cerel[512];
  float cedec[512];
  int cens[513];     // per meta-node index -> first csum edge (+ sentinel)
};
struct HostTree {
  TreeMeta meta;
  int n_levels;
  int level_off[520];
  int level_M[520];
};

static void build_tree_host(HostTree& T) {
  Pcg st; pcg_seed0(st);
  int parent[NN], depth[NN], rel[NN];
  unsigned char virt[NN];
  parent[0] = 0; depth[0] = 0;
  for (int i = 1; i < NN; i++) parent[i] = (int)pcg_bounded(st, (uint64_t)i);
  for (int i = 1; i < NN; i++) depth[i] = depth[parent[i]] + 1;
  for (int i = 0; i < NN; i++) rel[i] = (int)pcg_bounded(st, (uint64_t)NR);
  for (int i = 0; i < NN; i++) virt[i] = (pcg_double(st) < 0.1) ? 1 : 0;

  int childcnt[NN]; memset(childcnt, 0, sizeof(childcnt));
  for (int i = 1; i < NN; i++) childcnt[parent[i]]++;
  int maxd = 0;
  for (int i = 0; i < NN; i++) if (depth[i] > maxd) maxd = depth[i];

  int ni = 0, ne = 0, nec = 0;
  T.n_levels = 0;
  for (int d = maxd; d >= 0; d--) {
    int mstart = ni;
    for (int n = 0; n < NN; n++) {
      if (depth[n] == d && childcnt[n] > 0) {
        T.meta.nodes[ni] = n;
        T.meta.cstart[ni] = ne;
        T.meta.ccount[ni] = childcnt[n];
        T.meta.cens[ni] = nec;
        for (int i2 = 1; i2 < NN; i2++) {
          if (parent[i2] == n) {
            T.meta.echild[ne] = i2;
            T.meta.erel[ne] = rel[i2];
            T.meta.edecay[ne] = virt[i2] ? 0.7f : 1.0f;
            ne++;
            if (childcnt[i2] > 0) {  // leaf children contribute exactly 0 to c_sum
              T.meta.cechild[nec] = i2;
              T.meta.cerel[nec] = rel[i2];
              T.meta.cedec[nec] = virt[i2] ? 0.7f : 1.0f;
              nec++;
            }
          }
        }
        ni++;
      }
    }
    if (ni > mstart) {
      T.level_off[T.n_levels] = mstart;
      T.level_M[T.n_levels] = ni - mstart;
      T.n_levels++;
    }
  }
  T.meta.cens[ni] = nec;
}

// ======================= device helpers =======================
__device__ __forceinline__ uint16_t f2bf(float f) {
  uint32_t u = __float_as_uint(f);
  return (uint16_t)((u + 0x7fffu + ((u >> 16) & 1u)) >> 16);
}
__device__ __forceinline__ float bf2f(uint16_t b) {
  return __uint_as_float(((uint32_t)b) << 16);
}
__device__ __forceinline__ float sigm(float x) {
  return 1.f / (1.f + expf(-x));
}

// Stage rows x 64 bf16 tile into LDS with XOR swizzle: elem ^= (row&7)<<3
__device__ __forceinline__ void stage_bf16(uint16_t* __restrict__ sm,
    const uint16_t* __restrict__ src, int stride, int rows) {
  const int chunks = rows << 3;
  for (int cch = threadIdx.x; cch < chunks; cch += 256) {
    const int row = cch >> 3, k = (cch & 7) << 3;
    uint4 v = *(const uint4*)(src + (size_t)row * stride + k);
    *(uint4*)(sm + (((row << 6) + k) ^ ((row & 7) << 3))) = v;
  }
}
__device__ __forceinline__ void stage_f32(uint16_t* __restrict__ sm,
    const float* __restrict__ src, int stride, int rows) {
  const int chunks = rows << 3;
  for (int cch = threadIdx.x; cch < chunks; cch += 256) {
    const int row = cch >> 3, k = (cch & 7) << 3;
    const float* p = src + (size_t)row * stride + k;
    float4 a = *(const float4*)p, b = *(const float4*)(p + 4);
    uint4 w;
    w.x = (uint32_t)f2bf(a.x) | ((uint32_t)f2bf(a.y) << 16);
    w.y = (uint32_t)f2bf(a.z) | ((uint32_t)f2bf(a.w) << 16);
    w.z = (uint32_t)f2bf(b.x) | ((uint32_t)f2bf(b.y) << 16);
    w.w = (uint32_t)f2bf(b.z) | ((uint32_t)f2bf(b.w) << 16);
    *(uint4*)(sm + (((row << 6) + k) ^ ((row & 7) << 3))) = w;
  }
}
__device__ __forceinline__ bh8 fld(const uint16_t* __restrict__ sm, int row, int k) {
  return *(const bh8*)(sm + (((row << 6) + k) ^ ((row & 7) << 3)));
}

// h_sum row load/accumulate helpers (register double-buffer, static indices)
#define LDROW(BUF, CH) do { \
    const uint4* p_ = (const uint4*)(hbase + (size_t)(CH) * NH); \
    BUF[0]=p_[0]; BUF[1]=p_[1]; BUF[2]=p_[2]; BUF[3]=p_[3]; \
    BUF[4]=p_[4]; BUF[5]=p_[5]; BUF[6]=p_[6]; BUF[7]=p_[7]; } while (0)
#define ACCROW(BUF, W) do { const float w_ = (W); \
    _Pragma("unroll") for (int v_ = 0; v_ < 8; v_++) { \
      const uint16_t* pe_ = (const uint16_t*)&BUF[v_]; \
      _Pragma("unroll") for (int q_ = 0; q_ < 8; q_++) \
        hs[v_*8+q_] = fmaf(bf2f(pe_[q_]), w_, hs[v_*8+q_]); } } while (0)

// ======================= weight prep: transpose + bf16 =======================
__global__ __launch_bounds__(256) void k_prep(const float* __restrict__ We,
    const float* __restrict__ Wf, const float* __restrict__ Wi,
    const float* __restrict__ Wo, const float* __restrict__ Wu,
    uint16_t* __restrict__ WeT, uint16_t* __restrict__ WfT,
    uint16_t* __restrict__ WgT) {
  const int i = blockIdx.x * 256 + threadIdx.x;
  if (i < 65536) {
    const int n = i >> 8, k = i & 255;
    WeT[i] = f2bf(We[k * 256 + n]);
  }
  const int i2 = i - 65536;
  if (i2 >= 0 && i2 < 196608) {
    const int r = i2 >> 16, rem = i2 & 65535, n = rem >> 8, k = rem & 255;
    WfT[i2] = f2bf(Wf[r * 65536 + k * 256 + n]);
  }
  const int i3 = i - 262144;
  if (i3 >= 0 && i3 < 393216) {
    const int g = i3 >> 17, rem = i3 & 131071, n = rem >> 9, k = rem & 511;
    const float* S = (g == 0) ? Wi : (g == 1) ? Wo : Wu;
    WgT[i3] = f2bf(S[k * 256 + n]);
  }
}

// ======================= encoder: h_bf = x_enc = bf16(nf @ W_enc + b) ===============
__global__ __launch_bounds__(256) void k_enc(const float* __restrict__ nf,
    const uint16_t* __restrict__ WeT, const float* __restrict__ b_enc,
    uint16_t* __restrict__ h_bf, uint16_t* __restrict__ x_enc) {
  __shared__ __align__(16) uint16_t smA[128 * 64];
  __shared__ __align__(16) uint16_t smB[128 * 64];
  const int bm = blockIdx.x * 128, bn = blockIdx.y * 128;
  const int tid = threadIdx.x, wid = tid >> 6, lane = tid & 63;
  const int wr = wid >> 1, wc2 = wid & 1, lr = lane & 15, lk = (lane >> 4) << 3;
  f32x4 acc[4][4] = {};
  for (int k0 = 0; k0 < 256; k0 += 64) {
    __syncthreads();
    stage_f32(smA, nf + (size_t)bm * NH + k0, NH, 128);
    stage_bf16(smB, WeT + (size_t)bn * 256 + k0, 256, 128);
    __syncthreads();
#pragma unroll
    for (int ks = 0; ks < 2; ks++) {
      bh8 af[4], bfr[4];
#pragma unroll
      for (int i = 0; i < 4; i++) af[i] = fld(smA, wr * 64 + i * 16 + lr, ks * 32 + lk);
#pragma unroll
      for (int j = 0; j < 4; j++) bfr[j] = fld(smB, wc2 * 64 + j * 16 + lr, ks * 32 + lk);
#pragma unroll
      for (int i = 0; i < 4; i++)
#pragma unroll
        for (int j = 0; j < 4; j++)
          acc[i][j] = __builtin_amdgcn_mfma_f32_16x16x32_bf16(af[i], bfr[j], acc[i][j], 0, 0, 0);
    }
  }
#pragma unroll
  for (int i = 0; i < 4; i++) {
#pragma unroll
    for (int j = 0; j < 4; j++) {
      const int col = bn + wc2 * 64 + j * 16 + (lane & 15);
      const float be = b_enc[col];
#pragma unroll
      for (int r = 0; r < 4; r++) {
        const int row = bm + wr * 64 + i * 16 + (lane >> 4) * 4 + r;
        const uint16_t hv = f2bf(acc[i][j][r] + be);
        h_bf[(size_t)row * NH + col] = hv;
        x_enc[(size_t)row * NH + col] = hv;
      }
    }
  }
}

// ======================= score partials init: svp[b][nd][g] = h.w_attn (16-col) ===========
__global__ __launch_bounds__(256) void k_sv0(const uint16_t* __restrict__ h_bf,
    const float* __restrict__ w_attn, float* __restrict__ svp) {
  const int idx = blockIdx.x * 256 + threadIdx.x;  // (b*NN+nd)*16+g
  const int g = idx & 15;
  const size_t row = (size_t)(idx >> 4);
  const uint16_t* hp = h_bf + row * NH + g * 16;
  uint4 p0 = *(const uint4*)hp, p1 = *(const uint4*)(hp + 8);
  const uint16_t* e0 = (const uint16_t*)&p0;
  const uint16_t* e1 = (const uint16_t*)&p1;
  float s = 0.f;
#pragma unroll
  for (int u = 0; u < 8; u++) s = fmaf(bf2f(e0[u]), w_attn[g * 16 + u], s);
#pragma unroll
  for (int u = 0; u < 8; u++) s = fmaf(bf2f(e1[u]), w_attn[g * 16 + 8 + u], s);
  svp[idx] = s;
}

// ======================= fused per-level kernel, col-sliced (big levels) =======================
__global__ __launch_bounds__(256) void k_lvl(
    uint16_t* h_bf, float* c, float* __restrict__ svp,
    const uint16_t* __restrict__ x_enc,
    const uint16_t* __restrict__ WfT, const uint16_t* __restrict__ WgT,
    const float* __restrict__ b_f, const float* __restrict__ b_i,
    const float* __restrict__ b_o, const float* __restrict__ b_u,
    const float* __restrict__ rel_emb, const float* __restrict__ w_attn,
    const float* __restrict__ b_attn, float* __restrict__ out,
    const TreeMeta* __restrict__ tm, int nb) {
  __shared__ float sc[64 * 65];                           // 16.6 KB
  __shared__ float swa[256];
  __shared__ float sRE[3];
  __shared__ int chl[64]; __shared__ int rll[64]; __shared__ float dcl[64];
  __shared__ __align__(16) uint16_t hsum[4 * 4096];       // 32 KB (64 x 256)

  const int bx = blockIdx.x, mloc = bx >> 1, b0 = (bx & 1) * 64;
  const int cslice = blockIdx.y * 64;
  const int gi = nb + mloc;
  const int nd = tm->nodes[gi], cs = tm->cstart[gi], cc = tm->ccount[gi];
  const int ce0 = tm->cens[gi], nic = tm->cens[gi + 1] - ce0;
  const int tid = threadIdx.x, wid = tid >> 6, lane = tid & 63;
  const int lr2 = lane & 15, hi4 = (lane >> 4), lk = hi4 << 3;
  const int colw = cslice + wid * 16 + lr2;  // this lane's output column

  if (tid < cc) {
    chl[tid] = tm->echild[cs + tid];
    rll[tid] = tm->erel[cs + tid];
    dcl[tid] = tm->edecay[cs + tid];
  }
  swa[tid] = w_attn[tid];
  if (wid < 3) {  // sRE[r] = rel_emb[r] . w_attn
    float p = 0.f;
#pragma unroll
    for (int i = 0; i < 4; i++) p += rel_emb[wid * NH + lane + 64 * i] * w_attn[lane + 64 * i];
#pragma unroll
    for (int off = 32; off; off >>= 1) p += __shfl_down(p, off);
    if (lane == 0) sRE[wid] = p;
  }
  __syncthreads();

  // ---- scores from svp partials + softmax (fused, one thread per batch row) ----
  const float ba = b_attn[0];
  if (tid < 64) {
    const float* svpb = svp + (size_t)(b0 + tid) * NN * 16;
    for (int e = 0; e < cc; e++) {
      const float4* p = (const float4*)(svpb + chl[e] * 16);
      float4 a = p[0], b2 = p[1], c2 = p[2], d2 = p[3];
      float s = ((a.x + a.y) + (a.z + a.w)) + ((b2.x + b2.y) + (b2.z + b2.w)) +
                ((c2.x + c2.y) + (c2.z + c2.w)) + ((d2.x + d2.y) + (d2.z + d2.w));
      sc[tid * 65 + e] = sRE[rll[e]] + dcl[e] * s + ba;
    }
    float mx = -1e30f;
    for (int e = 0; e < cc; e++) mx = fmaxf(mx, sc[tid * 65 + e]);
    float ss = 0.f;
    for (int e = 0; e < cc; e++) ss += expf(sc[tid * 65 + e] - mx);
    const float inv = 1.0f / ss;
    for (int e = 0; e < cc; e++) sc[tid * 65 + e] = expf(sc[tid * 65 + e] - mx) * inv * dcl[e];
  }
  __syncthreads();

  // ---- h_sum (full 256-dim) -> LDS; 1-ahead register double-buffer ----
  const int sb = tid >> 2, sq = tid & 3;
  {
    float hs[64];
#pragma unroll
    for (int v = 0; v < 64; v++) hs[v] = 0.f;
    const uint16_t* hbase = h_bf + (size_t)(b0 + sb) * NN * NH + sq * 64;
    uint4 bufA[8], bufB[8];
    LDROW(bufA, chl[0]);
    int e = 0;
    for (; e + 2 <= cc; e += 2) {
      LDROW(bufB, chl[e + 1]);
      ACCROW(bufA, sc[sb * 65 + e]);
      if (e + 2 < cc) LDROW(bufA, chl[e + 2]);
      ACCROW(bufB, sc[sb * 65 + e + 1]);
    }
    if (e < cc) ACCROW(bufA, sc[sb * 65 + e]);
    uint16_t* sub = hsum + sq * 4096;
#pragma unroll
    for (int v = 0; v < 32; v++) {
      uint32_t pk = (uint32_t)f2bf(hs[2 * v]) | ((uint32_t)f2bf(hs[2 * v + 1]) << 16);
      const int elem = ((sb << 6) + 2 * v) ^ ((sb & 7) << 3);
      *(uint32_t*)(sub + elem) = pk;
    }
  }

  // ---- csum for this 64-col slice: direct-global MFMA, no barriers ----
  f32x4 csum[4] = {};
#pragma unroll 2
  for (int e = 0; e < nic; e++) {
    const int ch = tm->cechild[ce0 + e];
    const int rel = tm->cerel[ce0 + e];
    const float dec = tm->cedec[ce0 + e];
    const uint16_t* Wr = WfT + (size_t)rel * 65536 + (size_t)colw * 256;
    f32x4 facc[4] = {};
#pragma unroll
    for (int k0 = 0; k0 < 8; k0++) {
      const int kk = k0 * 32 + lk;
      bh8 af[4];
#pragma unroll
      for (int i = 0; i < 4; i++)
        af[i] = *(const bh8*)(h_bf + ((size_t)(b0 + i * 16 + lr2) * NN + ch) * NH + kk);
      const bh8 bq = *(const bh8*)(Wr + kk);
#pragma unroll
      for (int i = 0; i < 4; i++)
        facc[i] = __builtin_amdgcn_mfma_f32_16x16x32_bf16(af[i], bq, facc[i], 0, 0, 0);
    }
    const float bfv = b_f[rel * NH + colw];
#pragma unroll
    for (int i = 0; i < 4; i++) {
#pragma unroll
      for (int r = 0; r < 4; r++) {
        const int brow = b0 + i * 16 + hi4 * 4 + r;
        const float cch = c[((size_t)brow * NN + ch) * NH + colw];
        csum[i][r] += (dec * facc[i][r] + bfv) * (dec * cch);
      }
    }
  }
  __syncthreads();  // hsum writes visible before gates reads

  // ---- gates GEMM (K=512): A = x_enc[nd] (race-free) | hsum LDS; B = col slice ----
  f32x4 ga[3][4] = {};
#pragma unroll
  for (int k32 = 0; k32 < 16; k32++) {
    const int kk = k32 * 32 + lk;
    bh8 af[4], bq[3];
    if (k32 < 8) {
#pragma unroll
      for (int i = 0; i < 4; i++)
        af[i] = *(const bh8*)(x_enc + ((size_t)(b0 + i * 16 + lr2) * NN + nd) * NH + kk);
    } else {
      const int kx = k32 - 8;
#pragma unroll
      for (int i = 0; i < 4; i++)
        af[i] = fld(hsum + (kx >> 1) * 4096, i * 16 + lr2, (kx & 1) * 32 + lk);
    }
#pragma unroll
    for (int g = 0; g < 3; g++)
      bq[g] = *(const bh8*)(WgT + ((size_t)g << 17) + (size_t)colw * 512 + kk);
#pragma unroll
    for (int g = 0; g < 3; g++)
#pragma unroll
      for (int i = 0; i < 4; i++)
        ga[g][i] = __builtin_amdgcn_mfma_f32_16x16x32_bf16(af[i], bq[g], ga[g][i], 0, 0, 0);
  }

  const float bi_ = b_i[colw], bo_ = b_o[colw], bu_ = b_u[colw];
  const float wac = swa[colw];
#pragma unroll
  for (int i = 0; i < 4; i++) {
#pragma unroll
    for (int r = 0; r < 4; r++) {
      const int brow = b0 + i * 16 + hi4 * 4 + r;
      const size_t idx = ((size_t)brow * NN + nd) * NH + colw;
      const float ig = sigm(ga[0][i][r] + bi_);
      const float og = sigm(ga[1][i][r] + bo_);
      const float ug = tanhf(ga[2][i][r] + bu_);
      const float cn = fmaf(ig, ug, csum[i][r]);
      c[idx] = cn;
      const float hn = og * tanhf(cn);
      h_bf[idx] = f2bf(hn);
      if (nd == 0) out[(size_t)brow * NH + colw] = hn;
      // update score partials for this 16-col group
      float pv = hn * wac;
      pv += __shfl_xor(pv, 1); pv += __shfl_xor(pv, 2);
      pv += __shfl_xor(pv, 4); pv += __shfl_xor(pv, 8);
      if (lr2 == 0) svp[((size_t)brow * NN + nd) * 16 + (cslice >> 4) + wid] = pv;
    }
  }
}

// ======================= tiny-level kernel: fine col-tiled, max in-flight =======================
// grid = (16 col-slices of 16 cols, 2M batch-half x node). block = 64 rows x
// 16 cols, 4 waves (wave = 16x16 MFMA tile, wave w owns rows b0+w*16..+15).
__global__ __launch_bounds__(256) void k_tiny(
    uint16_t* h_bf, float* c, float* __restrict__ svp,
    const uint16_t* __restrict__ x_enc,
    const uint16_t* __restrict__ WfT, const uint16_t* __restrict__ WgT,
    const float* __restrict__ b_f, const float* __restrict__ b_i,
    const float* __restrict__ b_o, const float* __restrict__ b_u,
    const float* __restrict__ rel_emb, const float* __restrict__ w_attn,
    const float* __restrict__ b_attn, float* __restrict__ out,
    const TreeMeta* __restrict__ tm, int nb) {
  __shared__ float sc[64 * 65];                           // 16.6 KB
  __shared__ float swa[256];
  __shared__ float sRE[3];
  __shared__ int chl[64]; __shared__ int rll[64]; __shared__ float dcl[64];
  __shared__ __align__(16) uint16_t hsum[4 * 4096];       // 32 KB (64 x 256)

  const int c0 = blockIdx.x * 16;
  const int mloc = blockIdx.y >> 1, b0 = (blockIdx.y & 1) * 64;
  const int gi = nb + mloc;
  const int nd = tm->nodes[gi], cs = tm->cstart[gi], cc = tm->ccount[gi];
  const int ce0 = tm->cens[gi], nic = tm->cens[gi + 1] - ce0;
  const int tid = threadIdx.x, wid = tid >> 6, lane = tid & 63;
  const int lb = lane & 15, lq = lane >> 4;
  const int colw = c0 + lb;           // lane's output column
  const int wrow = b0 + wid * 16;     // wave's 16-row base

  if (tid < cc) {
    chl[tid] = tm->echild[cs + tid];
    rll[tid] = tm->erel[cs + tid];
    dcl[tid] = tm->edecay[cs + tid];
  }
  swa[tid] = w_attn[tid];
  if (wid < 3) {  // sRE[r] = rel_emb[r] . w_attn
    float p = 0.f;
#pragma unroll
    for (int i = 0; i < 4; i++) p += rel_emb[wid * NH + lane + 64 * i] * w_attn[lane + 64 * i];
#pragma unroll
    for (int off = 32; off; off >>= 1) p += __shfl_down(p, off);
    if (lane == 0) sRE[wid] = p;
  }
  __syncthreads();

  // ---- scores from svp partials + softmax (fused) ----
  const float ba = b_attn[0];
  if (tid < 64) {
    const float* svpb = svp + (size_t)(b0 + tid) * NN * 16;
    for (int e = 0; e < cc; e++) {
      const float4* p = (const float4*)(svpb + chl[e] * 16);
      float4 a = p[0], b2 = p[1], c2 = p[2], d2 = p[3];
      float s = ((a.x + a.y) + (a.z + a.w)) + ((b2.x + b2.y) + (b2.z + b2.w)) +
                ((c2.x + c2.y) + (c2.z + c2.w)) + ((d2.x + d2.y) + (d2.z + d2.w));
      sc[tid * 65 + e] = sRE[rll[e]] + dcl[e] * s + ba;
    }
    float mx = -1e30f;
    for (int e = 0; e < cc; e++) mx = fmaxf(mx, sc[tid * 65 + e]);
    float ss = 0.f;
    for (int e = 0; e < cc; e++) ss += expf(sc[tid * 65 + e] - mx);
    const float inv = 1.0f / ss;
    for (int e = 0; e < cc; e++) sc[tid * 65 + e] = expf(sc[tid * 65 + e] - mx) * inv * dcl[e];
  }
  __syncthreads();

  // ---- h_sum (full 256-dim) -> LDS; 1-ahead register double-buffer ----
  const int sb = tid >> 2, sq = tid & 3;
  {
    float hs[64];
#pragma unroll
    for (int v = 0; v < 64; v++) hs[v] = 0.f;
    const uint16_t* hbase = h_bf + (size_t)(b0 + sb) * NN * NH + sq * 64;
    uint4 bufA[8], bufB[8];
    LDROW(bufA, chl[0]);
    int e = 0;
    for (; e + 2 <= cc; e += 2) {
      LDROW(bufB, chl[e + 1]);
      ACCROW(bufA, sc[sb * 65 + e]);
      if (e + 2 < cc) LDROW(bufA, chl[e + 2]);
      ACCROW(bufB, sc[sb * 65 + e + 1]);
    }
    if (e < cc) ACCROW(bufA, sc[sb * 65 + e]);
    uint16_t* sub = hsum + sq * 4096;
#pragma unroll
    for (int v = 0; v < 32; v++) {
      uint32_t pk = (uint32_t)f2bf(hs[2 * v]) | ((uint32_t)f2bf(hs[2 * v + 1]) << 16);
      const int elem = ((sb << 6) + 2 * v) ^ ((sb & 7) << 3);
      *(uint32_t*)(sub + elem) = pk;
    }
  }

  // ---- csum: wave's 16 rows x block's 16 cols; direct-global MFMA ----
  f32x4 csum = {};
#pragma unroll 2
  for (int e = 0; e < nic; e++) {
    const int ch = tm->cechild[ce0 + e];
    const int rel = tm->cerel[ce0 + e];
    const float dec = tm->cedec[ce0 + e];
    const uint16_t* Wr = WfT + (size_t)rel * 65536 + (size_t)colw * 256;
    f32x4 facc = {};
#pragma unroll
    for (int k0 = 0; k0 < 8; k0++) {
      const int kk = k0 * 32 + lq * 8;
      const bh8 af = *(const bh8*)(h_bf + ((size_t)(wrow + lb) * NN + ch) * NH + kk);
      const bh8 bq = *(const bh8*)(Wr + kk);
      facc = __builtin_amdgcn_mfma_f32_16x16x32_bf16(af, bq, facc, 0, 0, 0);
    }
    const float bfv = b_f[rel * NH + colw];
#pragma unroll
    for (int r = 0; r < 4; r++) {
      const int brow = wrow + lq * 4 + r;
      const float cch = c[((size_t)brow * NN + ch) * NH + colw];
      csum[r] += (dec * facc[r] + bfv) * (dec * cch);
    }
  }
  __syncthreads();  // hsum visible

  // ---- gates (K=512): A = x_enc[nd] (race-free) | hsum LDS; B = 16-col slice ----
  f32x4 ga[3] = {};
#pragma unroll
  for (int k32 = 0; k32 < 16; k32++) {
    const int kk = k32 * 32 + lq * 8;
    bh8 af;
    if (k32 < 8) {
      af = *(const bh8*)(x_enc + ((size_t)(wrow + lb) * NN + nd) * NH + kk);
    } else {
      const int kx = k32 - 8;
      af = fld(hsum + (kx >> 1) * 4096, wid * 16 + lb, (kx & 1) * 32 + lq * 8);
    }
#pragma unroll
    for (int g = 0; g < 3; g++) {
      const bh8 bq = *(const bh8*)(WgT + ((size_t)g << 17) + (size_t)colw * 512 + kk);
      ga[g] = __builtin_amdgcn_mfma_f32_16x16x32_bf16(af, bq, ga[g], 0, 0, 0);
    }
  }

  const float bi_ = b_i[colw], bo_ = b_o[colw], bu_ = b_u[colw];
  const float wac = swa[colw];
#pragma unroll
  for (int r = 0; r < 4; r++) {
    const int brow = wrow + lq * 4 + r;
    const size_t idx = ((size_t)brow * NN + nd) * NH + colw;
    const float ig = sigm(ga[0][r] + bi_);
    const float og = sigm(ga[1][r] + bo_);
    const float ug = tanhf(ga[2][r] + bu_);
    const float cn = fmaf(ig, ug, csum[r]);
    c[idx] = cn;
    const float hn = og * tanhf(cn);
    h_bf[idx] = f2bf(hn);
    if (nd == 0) out[(size_t)brow * NH + colw] = hn;
    float pv = hn * wac;
    pv += __shfl_xor(pv, 1); pv += __shfl_xor(pv, 2);
    pv += __shfl_xor(pv, 4); pv += __shfl_xor(pv, 8);
    if (lb == 0) svp[((size_t)brow * NN + nd) * 16 + (c0 >> 4)] = pv;
  }
}

// ======================= launch =======================
extern "C" void kernel_launch(void* const* d_in, const int* in_sizes, int n_in,
                              void* d_out, int out_size, void* d_ws, size_t ws_size,
                              hipStream_t stream) {
  (void)in_sizes; (void)n_in; (void)out_size; (void)ws_size;
  const float* nf      = (const float*)d_in[0];
  const float* W_enc   = (const float*)d_in[1];
  const float* b_enc   = (const float*)d_in[2];
  const float* rel_emb = (const float*)d_in[3];
  const float* W_i     = (const float*)d_in[4];
  const float* b_i     = (const float*)d_in[5];
  const float* W_o     = (const float*)d_in[6];
  const float* b_o     = (const float*)d_in[7];
  const float* W_u     = (const float*)d_in[8];
  const float* b_u     = (const float*)d_in[9];
  const float* W_f     = (const float*)d_in[10];
  const float* b_f     = (const float*)d_in[11];
  const float* w_attn  = (const float*)d_in[12];
  const float* b_attn  = (const float*)d_in[13];
  float* out = (float*)d_out;

  static HostTree T;  // rebuilt identically every call (deterministic)
  build_tree_host(T);

  char* ws = (char*)d_ws;
  const size_t OFF_HBF = 32768;
  const size_t SZ_HBF  = (size_t)NB * NN * NH * 2;  // 33.5 MB
  const size_t OFF_XE  = OFF_HBF + SZ_HBF;          // 33.5 MB (pristine encoder h)
  const size_t OFF_WET = OFF_XE + SZ_HBF;
  const size_t OFF_WFT = OFF_WET + 131072;
  const size_t OFF_WGT = OFF_WFT + 393216;
  const size_t OFF_C   = OFF_WGT + 786432;          // 67 MB fp32
  const size_t SZ_C    = (size_t)NB * NN * NH * 4;
  const size_t OFF_SVP = OFF_C + SZ_C;              // 4 MB fp32

  TreeMeta* dm = (TreeMeta*)ws;
  uint16_t* h_bf = (uint16_t*)(ws + OFF_HBF);
  uint16_t* x_enc = (uint16_t*)(ws + OFF_XE);
  uint16_t* WeT = (uint16_t*)(ws + OFF_WET);
  uint16_t* WfT = (uint16_t*)(ws + OFF_WFT);
  uint16_t* WgT = (uint16_t*)(ws + OFF_WGT);
  float* c = (float*)(ws + OFF_C);
  float* svp = (float*)(ws + OFF_SVP);

  hipMemcpyAsync(dm, &T.meta, sizeof(TreeMeta), hipMemcpyHostToDevice, stream);

  k_prep<<<2560, 256, 0, stream>>>(W_enc, W_f, W_i, W_o, W_u, WeT, WfT, WgT);
  k_enc<<<dim3((NB * NN) / 128, 2), 256, 0, stream>>>(nf, WeT, b_enc, h_bf, x_enc);
  k_sv0<<<dim3((NB * NN * 16) / 256), 256, 0, stream>>>(h_bf, w_attn, svp);

  for (int l = 0; l < T.n_levels; l++) {
    const int Mfull = T.level_M[l];
    if (Mfull >= TH_TINY) {
      for (int c0 = 0; c0 < Mfull; c0 += 128) {
        const int Mc = (Mfull - c0) < 128 ? (Mfull - c0) : 128;
        k_lvl<<<dim3(2 * Mc, 4), 256, 0, stream>>>(h_bf, c, svp, x_enc, WfT, WgT,
            b_f, b_i, b_o, b_u, rel_emb, w_attn, b_attn, out, dm,
            T.level_off[l] + c0);
      }
    } else {
      k_tiny<<<dim3(16, 2 * Mfull), 256, 0, stream>>>(h_bf, c, svp, x_enc, WfT, WgT,
          b_f, b_i, b_o, b_u, rel_emb, w_attn, b_attn, out, dm,
          T.level_off[l]);
    }
  }
}